// Round 5
// baseline (123.249 us; speedup 1.0000x reference)
//
#include <hip/hip_runtime.h>
#include <hip/hip_bf16.h>
#include <math.h>

#define IMG 256

typedef __attribute__((ext_vector_type(4))) short short4v;
typedef __attribute__((ext_vector_type(8))) short short8v;
typedef __attribute__((ext_vector_type(4))) float f32x4;

__device__ __forceinline__ short bf16s(float f) {
    __hip_bfloat16 h = __float2bfloat16(f);
    short s; __builtin_memcpy(&s, &h, 2); return s;
}
__device__ __forceinline__ unsigned int bf16u(float f) {
    return (unsigned int)(unsigned short)bf16s(f);
}
__device__ __forceinline__ float bflo(unsigned int v) { return __uint_as_float(v << 16); }
__device__ __forceinline__ float bfhi(unsigned int v) { return __uint_as_float(v & 0xffff0000u); }

// ---------------- Kernel 1: gating conv 7x7 s4 + relu + partial sums via MFMA --
// grid (16 tiles = 8 row x 2 col, 64 batch), 256 threads
// xs[r][c] = x[32rt-1+r][128ct-1+c]  (c = gx - 128ct + 1, stride 136)
__global__ __launch_bounds__(256) void gate_mfma_kernel(
    const float* __restrict__ x, const float* __restrict__ Wg,
    float* __restrict__ partials)
{
    __shared__ short xs[36 * 136];
    __shared__ short whi[64 * 66];     // [k][gf], k = ky*8+kx (pads zero)
    __shared__ short wlo[64 * 66];
    __shared__ float red[4][64];

    const int tile = blockIdx.x;       // 0..15
    const int rt = tile >> 1, ct = tile & 1;
    const int b   = blockIdx.y;
    const int tid = threadIdx.x;

    // ---- W staging (hi+lo bf16 split) ----
    for (int i = tid; i < 64 * 64; i += 256) {
        const int k = i >> 6, gf = i & 63;
        const int ky = k >> 3, kx = k & 7;
        float wv = 0.f;
        if (kx < 7 && ky < 7) wv = Wg[gf * 49 + ky * 7 + kx];
        const short hi = bf16s(wv);
        const float hif = __uint_as_float(((unsigned int)(unsigned short)hi) << 16);
        whi[k * 66 + gf] = hi;
        wlo[k * 66 + gf] = bf16s(wv - hif);
    }

    // ---- x staging, vectorized float4 ----
    const float* xb = x + (size_t)b * (IMG * IMG);
    const int gy0 = rt * 32 - 1;
    {
        const int qx = tid & 31;       // quad -> xs cols 1+4qx .. 4+4qx
        const int rb = tid >> 5;       // 0..7
        #pragma unroll
        for (int t = 0; t < 5; ++t) {
            const int r = rb + 8 * t;
            if (r < 36) {
                const int gy = gy0 + r;
                float4 v = make_float4(0.f, 0.f, 0.f, 0.f);
                if (gy >= 0 && gy < IMG)
                    v = *(const float4*)&xb[gy * IMG + 128 * ct + 4 * qx];
                short* p = &xs[r * 136 + 4 * qx + 1];
                p[0] = bf16s(v.x); p[1] = bf16s(v.y); p[2] = bf16s(v.z); p[3] = bf16s(v.w);
            }
        }
    }
    if (tid < 36) {                    // col 0 (gx = 128ct-1)
        const int r = tid, gy = gy0 + r;
        float v = 0.f;
        if (gy >= 0 && gy < IMG && ct == 1) v = xb[gy * IMG + 127];
        xs[r * 136] = bf16s(v);
    }
    if (tid < 36) {                    // cols 129..132 (gx = 128ct+128..131)
        const int r = tid, gy = gy0 + r;
        float4 v = make_float4(0.f, 0.f, 0.f, 0.f);
        if (gy >= 0 && gy < IMG && ct == 0)
            v = *(const float4*)&xb[gy * IMG + 128];
        short* p = &xs[r * 136 + 129];
        p[0] = bf16s(v.x); p[1] = bf16s(v.y); p[2] = bf16s(v.z); p[3] = bf16s(v.w);
    }
    __syncthreads();

    const int lane = tid & 63;
    const int wv_  = tid >> 6;   // wave 0..3
    const int m    = lane & 15;
    const int kb   = lane >> 4;  // 0..3

    // B frags: lane holds B[k=(kb+4s)*8+j][nc*16+m]
    short8v Bhi[2][4], Blo[2][4];
    #pragma unroll
    for (int s = 0; s < 2; ++s) {
        const int kbg = kb + 4 * s;
        #pragma unroll
        for (int nc = 0; nc < 4; ++nc) {
            short8v bh, bl;
            #pragma unroll
            for (int j = 0; j < 8; ++j) {
                bh[j] = whi[(kbg * 8 + j) * 66 + nc * 16 + m];
                bl[j] = wlo[(kbg * 8 + j) * 66 + nc * 16 + m];
            }
            Bhi[s][nc] = bh; Blo[s][nc] = bl;
        }
    }

    float rsum[4] = {0.f, 0.f, 0.f, 0.f};
    const f32x4 zero4 = {0.f, 0.f, 0.f, 0.f};

    #pragma unroll 1
    for (int i = 0; i < 4; ++i) {            // 4 chunks per wave, 16 per block
        const int chunk = wv_ * 4 + i;
        const int r = chunk >> 1, q = chunk & 1;   // out row r, col group 16*(2ct)+...
        short8v A[2];
        #pragma unroll
        for (int s = 0; s < 2; ++s) {
            const int row = 4 * r + kb + 4 * s;
            const short4v* p = (const short4v*)&xs[row * 136 + 64 * q + 4 * m];
            const short4v lo4 = p[0], hi4 = p[1];
            A[s] = __builtin_shufflevector(lo4, hi4, 0, 1, 2, 3, 4, 5, 6, 7);
        }
        #pragma unroll
        for (int nc = 0; nc < 4; ++nc) {
            f32x4 z = __builtin_amdgcn_mfma_f32_16x16x32_bf16(A[0], Bhi[0][nc], zero4, 0, 0, 0);
            z = __builtin_amdgcn_mfma_f32_16x16x32_bf16(A[1], Bhi[1][nc], z, 0, 0, 0);
            z = __builtin_amdgcn_mfma_f32_16x16x32_bf16(A[0], Blo[0][nc], z, 0, 0, 0);
            z = __builtin_amdgcn_mfma_f32_16x16x32_bf16(A[1], Blo[1][nc], z, 0, 0, 0);
            rsum[nc] += fmaxf(z[0], 0.f) + fmaxf(z[1], 0.f) + fmaxf(z[2], 0.f) + fmaxf(z[3], 0.f);
        }
    }

    #pragma unroll
    for (int nc = 0; nc < 4; ++nc) {
        float v = rsum[nc];
        v += __shfl_xor(v, 16);
        v += __shfl_xor(v, 32);
        if (lane < 16) red[wv_][nc * 16 + lane] = v;
    }
    __syncthreads();
    if (tid < 64) {
        const float s = red[0][tid] + red[1][tid] + red[2][tid] + red[3][tid];
        partials[(b * 16 + tile) * 64 + tid] = s;
    }
}

// ---------------- Kernel 2: gating finalize (feats -> heads -> weights) --------
__global__ void gate_finalize_kernel(
    const float* __restrict__ partials,
    const float* __restrict__ Wc, const float* __restrict__ bc,
    const float* __restrict__ Wp, const float* __restrict__ bp,
    int* __restrict__ gidx, float* __restrict__ gw)
{
    const int b = threadIdx.x;   // 64 threads
    float f[64];
    #pragma unroll
    for (int g = 0; g < 64; ++g) f[g] = 0.f;
    const float* pb = partials + b * 1024;   // 16 tiles x 64 gf
    #pragma unroll
    for (int t = 0; t < 16; ++t)
        #pragma unroll
        for (int g4 = 0; g4 < 16; ++g4) {
            const float4 v = *(const float4*)&pb[t * 64 + (g4 << 2)];
            f[(g4 << 2) + 0] += v.x;
            f[(g4 << 2) + 1] += v.y;
            f[(g4 << 2) + 2] += v.z;
            f[(g4 << 2) + 3] += v.w;
        }
    #pragma unroll
    for (int g = 0; g < 64; ++g) f[g] *= (1.0f / 4096.0f);

    float cl[6], pl[2];
    #pragma unroll
    for (int j = 0; j < 6; ++j) {
        float s = bc[j];
        #pragma unroll
        for (int g = 0; g < 64; ++g) s += f[g] * Wc[j * 64 + g];
        cl[j] = s;
    }
    #pragma unroll
    for (int j = 0; j < 2; ++j) {
        float s = bp[j];
        #pragma unroll
        for (int g = 0; g < 64; ++g) s += f[g] * Wp[j * 64 + g];
        pl[j] = s;
    }
    const float pm = fmaxf(pl[0], pl[1]);
    const float e0 = expf(pl[0] - pm), e1 = expf(pl[1] - pm);
    const int   pi = (pl[1] > pl[0]) ? 1 : 0;
    const float pv = fmaxf(e0, e1) / (e0 + e1);
    float cm = cl[0];
    #pragma unroll
    for (int j = 1; j < 6; ++j) cm = fmaxf(cm, cl[j]);
    float es = 0.f, ce[6];
    #pragma unroll
    for (int j = 0; j < 6; ++j) { ce[j] = expf(cl[j] - cm); es += ce[j]; }
    int ci = 0; float cbest = cl[0];
    #pragma unroll
    for (int j = 1; j < 6; ++j) if (cl[j] > cbest) { cbest = cl[j]; ci = j; }
    const float cv = ce[ci] / es;

    const float wp = 0.3f * pv;
    const float wc = 0.7f * cv;
    const float tot = wp + wc + 1e-8f;
    gidx[b]      = pi;
    gidx[64 + b] = ci + 2;
    gw[b]        = wp / tot;
    gw[64 + b]   = wc / tot;
}

// ---------------- Kernel 3: fused two-expert conv3x3 -> relu -> conv3x3 -------
// grid (64 tiles of 32x32, 64 batch), 256 threads. hs bf16, row stride 36.
__global__ __launch_bounds__(256) void expert_kernel(
    const float* __restrict__ x,
    const float* __restrict__ We1, const float* __restrict__ be1,
    const float* __restrict__ We2, const float* __restrict__ be2,
    const int* __restrict__ gidx, const float* __restrict__ gw,
    float* __restrict__ out)
{
    __shared__ float xs[36 * 40];                             // fp32 x tile + halo2
    __shared__ __align__(16) unsigned short hs[8 * 34 * 36];  // bf16 h, stride 36

    const int tile = blockIdx.x;
    const int b    = blockIdx.y;
    const int ty = tile >> 3, tx = tile & 7;
    const int y0 = ty * 32, x0 = tx * 32;
    const int tid = threadIdx.x;
    const bool interior = (ty != 0) && (ty != 7) && (tx != 0) && (tx != 7);

    const float* xb = x + (size_t)b * (IMG * IMG);
    if (interior) {
        // rows 0..31 x cols 0..31
        {
            const int r = tid >> 3, qx = tid & 7;
            const float* gp = xb + (y0 - 2 + r) * IMG + (x0 - 2) + 4 * qx;
            const float2 u = *(const float2*)gp;
            const float2 v = *(const float2*)(gp + 2);
            *(float4*)&xs[r * 40 + 4 * qx] = make_float4(u.x, u.y, v.x, v.y);
        }
        if (tid < 32) {   // rows 32..35 x cols 0..31
            const int r = 32 + (tid >> 3), qx = tid & 7;
            const float* gp = xb + (y0 - 2 + r) * IMG + (x0 - 2) + 4 * qx;
            const float2 u = *(const float2*)gp;
            const float2 v = *(const float2*)(gp + 2);
            *(float4*)&xs[r * 40 + 4 * qx] = make_float4(u.x, u.y, v.x, v.y);
        }
        if (tid < 72) {   // all rows x cols 32..39
            const int r = tid >> 1, qx = 8 + (tid & 1);
            const float* gp = xb + (y0 - 2 + r) * IMG + (x0 - 2) + 4 * qx;
            const float2 u = *(const float2*)gp;
            const float2 v = *(const float2*)(gp + 2);
            *(float4*)&xs[r * 40 + 4 * qx] = make_float4(u.x, u.y, v.x, v.y);
        }
    } else {
        for (int i = tid; i < 36 * 40; i += 256) {
            int r = i / 40, c = i - r * 40;
            float v = 0.f;
            if (c < 36) {
                int gy = y0 - 2 + r, gx = x0 - 2 + c;
                if (gy >= 0 && gy < IMG && gx >= 0 && gx < IMG) v = xb[gy * IMG + gx];
            }
            xs[i] = v;
        }
    }

    const int ep = __builtin_amdgcn_readfirstlane(gidx[b]);
    const int ec = __builtin_amdgcn_readfirstlane(gidx[64 + b]);
    const float wA = __uint_as_float(__builtin_amdgcn_readfirstlane(__float_as_uint(gw[b])));
    const float wB = __uint_as_float(__builtin_amdgcn_readfirstlane(__float_as_uint(gw[64 + b])));

    const int r_ = tid >> 3;          // 0..31 output row
    const int c0 = (tid & 7) << 2;    // output col group (4 cols)
    const int c1ch   = tid >> 5;      // conv1: channel 0..7
    const int lane32 = tid & 31;
    const int hb  = lane32 >> 3;          // conv1 row phase 0..3
    const int cbm = (lane32 & 7) << 2;    // conv1 col quad 0..28

    float oacc0 = 0.f, oacc1 = 0.f, oacc2 = 0.f, oacc3 = 0.f;

    __syncthreads();

    for (int ei = 0; ei < 2; ++ei) {
        const int   e   = ei ? ec : ep;
        const float wgt = ei ? wB : wA;

        float w1r[9];
        const float* w1p = We1 + e * 72 + c1ch * 9;
        #pragma unroll
        for (int k = 0; k < 9; ++k) w1r[k] = w1p[k];
        const float b1r = be1[e * 8 + c1ch];

        if (ei) __syncthreads();   // prev conv2 reads done before hs overwrite

        // ---- conv1: h = relu(conv(x) + b1) in bf16 ----
        if (interior) {
            #pragma unroll 1
            for (int t = 0; t < 9; ++t) {
                const int hy = hb + 4 * t;
                if (hy < 34) {
                    float a0 = b1r, a1 = b1r, a2 = b1r, a3 = b1r;
                    #pragma unroll
                    for (int ky = 0; ky < 3; ++ky) {
                        const float* xr = &xs[(hy + ky) * 40 + cbm];
                        const float4 xa = *(const float4*)xr;
                        const float2 xc = *(const float2*)(xr + 4);
                        const float wa = w1r[ky * 3], wb = w1r[ky * 3 + 1], wcc = w1r[ky * 3 + 2];
                        a0 += wa * xa.x + wb * xa.y + wcc * xa.z;
                        a1 += wa * xa.y + wb * xa.z + wcc * xa.w;
                        a2 += wa * xa.z + wb * xa.w + wcc * xc.x;
                        a3 += wa * xa.w + wb * xc.x + wcc * xc.y;
                    }
                    const unsigned int lo = bf16u(fmaxf(a0, 0.f)) | (bf16u(fmaxf(a1, 0.f)) << 16);
                    const unsigned int hi = bf16u(fmaxf(a2, 0.f)) | (bf16u(fmaxf(a3, 0.f)) << 16);
                    *(uint2*)&hs[c1ch * 1224 + hy * 36 + cbm] = make_uint2(lo, hi);
                }
            }
            // tail: hx 32,33
            #pragma unroll 1
            for (int tt = 0; tt < 2; ++tt) {
                const int hy = lane32 + 32 * tt;
                if (hy < 34) {
                    float a0 = b1r, a1 = b1r;
                    #pragma unroll
                    for (int ky = 0; ky < 3; ++ky) {
                        const float4 xa = *(const float4*)&xs[(hy + ky) * 40 + 32];
                        a0 += w1r[ky * 3] * xa.x + w1r[ky * 3 + 1] * xa.y + w1r[ky * 3 + 2] * xa.z;
                        a1 += w1r[ky * 3] * xa.y + w1r[ky * 3 + 1] * xa.z + w1r[ky * 3 + 2] * xa.w;
                    }
                    *(unsigned int*)&hs[c1ch * 1224 + hy * 36 + 32] =
                        bf16u(fmaxf(a0, 0.f)) | (bf16u(fmaxf(a1, 0.f)) << 16);
                }
            }
        } else {
            #pragma unroll 1
            for (int t = 0; t < 9; ++t) {
                const int hy = hb + 4 * t;
                if (hy < 34) {
                    float a0 = b1r, a1 = b1r, a2 = b1r, a3 = b1r;
                    #pragma unroll
                    for (int ky = 0; ky < 3; ++ky) {
                        const float* xr = &xs[(hy + ky) * 40 + cbm];
                        const float4 xa = *(const float4*)xr;
                        const float2 xc = *(const float2*)(xr + 4);
                        const float wa = w1r[ky * 3], wb = w1r[ky * 3 + 1], wcc = w1r[ky * 3 + 2];
                        a0 += wa * xa.x + wb * xa.y + wcc * xa.z;
                        a1 += wa * xa.y + wb * xa.z + wcc * xa.w;
                        a2 += wa * xa.z + wb * xa.w + wcc * xc.x;
                        a3 += wa * xa.w + wb * xc.x + wcc * xc.y;
                    }
                    const int gy = y0 - 1 + hy;
                    const int gx = x0 - 1 + cbm;
                    const bool rowok = (gy >= 0) && (gy < IMG);
                    const float h0 = (rowok && gx >= 0) ? fmaxf(a0, 0.f) : 0.f;
                    const float h1 = rowok ? fmaxf(a1, 0.f) : 0.f;
                    const float h2 = rowok ? fmaxf(a2, 0.f) : 0.f;
                    const float h3 = rowok ? fmaxf(a3, 0.f) : 0.f;
                    const unsigned int lo = bf16u(h0) | (bf16u(h1) << 16);
                    const unsigned int hi = bf16u(h2) | (bf16u(h3) << 16);
                    *(uint2*)&hs[c1ch * 1224 + hy * 36 + cbm] = make_uint2(lo, hi);
                }
            }
            #pragma unroll 1
            for (int tt = 0; tt < 2; ++tt) {
                const int hy = lane32 + 32 * tt;
                if (hy < 34) {
                    float a0 = b1r, a1 = b1r;
                    #pragma unroll
                    for (int ky = 0; ky < 3; ++ky) {
                        const float4 xa = *(const float4*)&xs[(hy + ky) * 40 + 32];
                        a0 += w1r[ky * 3] * xa.x + w1r[ky * 3 + 1] * xa.y + w1r[ky * 3 + 2] * xa.z;
                        a1 += w1r[ky * 3] * xa.y + w1r[ky * 3 + 1] * xa.z + w1r[ky * 3 + 2] * xa.w;
                    }
                    const int gy = y0 - 1 + hy;
                    const bool rowok = (gy >= 0) && (gy < IMG);
                    const float h0 = rowok ? fmaxf(a0, 0.f) : 0.f;
                    const float h1 = (rowok && (x0 + 32) < IMG) ? fmaxf(a1, 0.f) : 0.f;
                    *(unsigned int*)&hs[c1ch * 1224 + hy * 36 + 32] =
                        bf16u(h0) | (bf16u(h1) << 16);
                }
            }
        }
        __syncthreads();

        // ---- conv2: y = conv(h) + b2, accumulate with gate weight ----
        float a0 = 0.f, a1 = 0.f, a2 = 0.f, a3 = 0.f;
        #pragma unroll
        for (int ch = 0; ch < 8; ++ch) {
            const float* w2p = We2 + e * 72 + ch * 9;   // e uniform -> s_load
            float w2r[9];
            #pragma unroll
            for (int k = 0; k < 9; ++k) w2r[k] = w2p[k];
            #pragma unroll
            for (int ky = 0; ky < 3; ++ky) {
                const unsigned short* hp = &hs[ch * 1224 + (r_ + ky) * 36 + c0];
                const uint2 q4 = *(const uint2*)hp;
                const unsigned int q2 = *(const unsigned int*)(hp + 4);
                const float h0 = bflo(q4.x), h1 = bfhi(q4.x);
                const float h2 = bflo(q4.y), h3 = bfhi(q4.y);
                const float h4 = bflo(q2),   h5 = bfhi(q2);
                const float wa = w2r[ky * 3], wb = w2r[ky * 3 + 1], wcx = w2r[ky * 3 + 2];
                a0 += wa * h0 + wb * h1 + wcx * h2;
                a1 += wa * h1 + wb * h2 + wcx * h3;
                a2 += wa * h2 + wb * h3 + wcx * h4;
                a3 += wa * h3 + wb * h4 + wcx * h5;
            }
        }
        const float b2v = be2[e];
        oacc0 += wgt * (a0 + b2v);
        oacc1 += wgt * (a1 + b2v);
        oacc2 += wgt * (a2 + b2v);
        oacc3 += wgt * (a3 + b2v);
    }

    const float4 o4 = make_float4(oacc0, oacc1, oacc2, oacc3);
    *(float4*)&out[(size_t)b * (IMG * IMG) + (y0 + r_) * IMG + (x0 + c0)] = o4;
}

extern "C" void kernel_launch(void* const* d_in, const int* in_sizes, int n_in,
                              void* d_out, int out_size, void* d_ws, size_t ws_size,
                              hipStream_t stream) {
    const float* x   = (const float*)d_in[0];
    const float* Wg  = (const float*)d_in[1];
    const float* Wc  = (const float*)d_in[2];
    const float* bc  = (const float*)d_in[3];
    const float* Wp  = (const float*)d_in[4];
    const float* bp  = (const float*)d_in[5];
    const float* We1 = (const float*)d_in[6];
    const float* be1 = (const float*)d_in[7];
    const float* We2 = (const float*)d_in[8];
    const float* be2 = (const float*)d_in[9];
    float* out = (float*)d_out;

    float* partials = (float*)d_ws;                              // 64*16*64 floats = 256 KB
    int*   gidx     = (int*)((char*)d_ws + 262144);              // 128 ints
    float* gw       = (float*)((char*)d_ws + 262144 + 512);      // 128 floats

    gate_mfma_kernel<<<dim3(16, 64), dim3(256), 0, stream>>>(x, Wg, partials);
    gate_finalize_kernel<<<dim3(1), dim3(64), 0, stream>>>(partials, Wc, bc, Wp, bp, gidx, gw);
    expert_kernel<<<dim3(64, 64), dim3(256), 0, stream>>>(x, We1, be1, We2, be2, gidx, gw, out);
}

// Round 6
// 116.431 us; speedup vs baseline: 1.0586x; 1.0586x over previous
//
#include <hip/hip_runtime.h>
#include <hip/hip_bf16.h>
#include <math.h>

#define IMG 256

typedef __attribute__((ext_vector_type(4))) short short4v;
typedef __attribute__((ext_vector_type(8))) short short8v;
typedef __attribute__((ext_vector_type(4))) float f32x4;

__device__ __forceinline__ short bf16s(float f) {
    __hip_bfloat16 h = __float2bfloat16(f);
    short s; __builtin_memcpy(&s, &h, 2); return s;
}
__device__ __forceinline__ unsigned int bf16u(float f) {
    return (unsigned int)(unsigned short)bf16s(f);
}
__device__ __forceinline__ float bflo(unsigned int v) { return __uint_as_float(v << 16); }
__device__ __forceinline__ float bfhi(unsigned int v) { return __uint_as_float(v & 0xffff0000u); }

// ---------------- Kernel 0: pack gating W into MFMA B-fragment layout ---------
// lane l (64): kb=l>>4, m=l&15. frag (s,nc): B[k=(kb+4s)*8+j][gf=nc*16+m]
// stored at bpack[((s*4+nc)*64 + l)*8 + j]  (hi and lo bf16 split)
__global__ void gate_prep_kernel(const float* __restrict__ Wg,
                                 short* __restrict__ bhi, short* __restrict__ blo)
{
    const int l = threadIdx.x;          // 0..63
    const int kb = l >> 4, m = l & 15;
    #pragma unroll
    for (int s = 0; s < 2; ++s) {
        const int ky = kb + 4 * s;      // 0..7 (7 = zero pad row)
        #pragma unroll
        for (int nc = 0; nc < 4; ++nc) {
            const int gf = nc * 16 + m;
            #pragma unroll
            for (int j = 0; j < 8; ++j) {   // kx (7 = zero pad col)
                float wv = 0.f;
                if (j < 7 && ky < 7) wv = Wg[gf * 49 + ky * 7 + j];
                const short hi = bf16s(wv);
                const float hif = __uint_as_float(((unsigned int)(unsigned short)hi) << 16);
                const int idx = ((s * 4 + nc) * 64 + l) * 8 + j;
                bhi[idx] = hi;
                blo[idx] = bf16s(wv - hif);
            }
        }
    }
}

// ---------------- Kernel 1: gating conv 7x7 s4 + relu + partial sums via MFMA --
// grid (16 tiles = 8 row x 2 col, 64 batch), 256 threads
// xs[r][c] = x[32rt-1+r][128ct-1+c]  (stride 136)
__global__ __launch_bounds__(256) void gate_mfma_kernel(
    const float* __restrict__ x,
    const short* __restrict__ bhi, const short* __restrict__ blo,
    float* __restrict__ partials)
{
    __shared__ short xs[36 * 136];
    __shared__ float red[4][64];

    const int tile = blockIdx.x;       // 0..15
    const int rt = tile >> 1, ct = tile & 1;
    const int b   = blockIdx.y;
    const int tid = threadIdx.x;

    // ---- x staging, vectorized float4 ----
    const float* xb = x + (size_t)b * (IMG * IMG);
    const int gy0 = rt * 32 - 1;
    {
        const int qx = tid & 31;       // quad -> xs cols 1+4qx .. 4+4qx
        const int rb = tid >> 5;       // 0..7
        #pragma unroll
        for (int t = 0; t < 5; ++t) {
            const int r = rb + 8 * t;
            if (r < 36) {
                const int gy = gy0 + r;
                float4 v = make_float4(0.f, 0.f, 0.f, 0.f);
                if (gy >= 0 && gy < IMG)
                    v = *(const float4*)&xb[gy * IMG + 128 * ct + 4 * qx];
                short* p = &xs[r * 136 + 4 * qx + 1];
                p[0] = bf16s(v.x); p[1] = bf16s(v.y); p[2] = bf16s(v.z); p[3] = bf16s(v.w);
            }
        }
    }
    if (tid < 36) {                    // col 0 (gx = 128ct-1)
        const int r = tid, gy = gy0 + r;
        float v = 0.f;
        if (gy >= 0 && gy < IMG && ct == 1) v = xb[gy * IMG + 127];
        xs[r * 136] = bf16s(v);
    }
    if (tid < 36) {                    // cols 129..132 (gx = 128ct+128..131)
        const int r = tid, gy = gy0 + r;
        float4 v = make_float4(0.f, 0.f, 0.f, 0.f);
        if (gy >= 0 && gy < IMG && ct == 0)
            v = *(const float4*)&xb[gy * IMG + 128];
        short* p = &xs[r * 136 + 129];
        p[0] = bf16s(v.x); p[1] = bf16s(v.y); p[2] = bf16s(v.z); p[3] = bf16s(v.w);
    }

    const int lane = tid & 63;
    const int wv_  = tid >> 6;   // wave 0..3
    const int m    = lane & 15;
    const int kb   = lane >> 4;  // 0..3

    // ---- B fragments: coalesced 16B global loads (L2-resident broadcast) ----
    short8v Bhi[2][4], Blo[2][4];
    #pragma unroll
    for (int s = 0; s < 2; ++s)
        #pragma unroll
        for (int nc = 0; nc < 4; ++nc) {
            const int base = ((s * 4 + nc) * 64 + lane) * 8;
            Bhi[s][nc] = *(const short8v*)&bhi[base];
            Blo[s][nc] = *(const short8v*)&blo[base];
        }

    __syncthreads();

    float rsum[4] = {0.f, 0.f, 0.f, 0.f};
    const f32x4 zero4 = {0.f, 0.f, 0.f, 0.f};

    #pragma unroll 1
    for (int i = 0; i < 4; ++i) {            // 4 chunks per wave, 16 per block
        const int chunk = wv_ * 4 + i;
        const int r = chunk >> 1, q = chunk & 1;
        short8v A[2];
        #pragma unroll
        for (int s = 0; s < 2; ++s) {
            const int row = 4 * r + kb + 4 * s;
            const short4v* p = (const short4v*)&xs[row * 136 + 64 * q + 4 * m];
            const short4v lo4 = p[0], hi4 = p[1];
            A[s] = __builtin_shufflevector(lo4, hi4, 0, 1, 2, 3, 4, 5, 6, 7);
        }
        #pragma unroll
        for (int nc = 0; nc < 4; ++nc) {
            f32x4 z = __builtin_amdgcn_mfma_f32_16x16x32_bf16(A[0], Bhi[0][nc], zero4, 0, 0, 0);
            z = __builtin_amdgcn_mfma_f32_16x16x32_bf16(A[1], Bhi[1][nc], z, 0, 0, 0);
            z = __builtin_amdgcn_mfma_f32_16x16x32_bf16(A[0], Blo[0][nc], z, 0, 0, 0);
            z = __builtin_amdgcn_mfma_f32_16x16x32_bf16(A[1], Blo[1][nc], z, 0, 0, 0);
            rsum[nc] += fmaxf(z[0], 0.f) + fmaxf(z[1], 0.f) + fmaxf(z[2], 0.f) + fmaxf(z[3], 0.f);
        }
    }

    #pragma unroll
    for (int nc = 0; nc < 4; ++nc) {
        float v = rsum[nc];
        v += __shfl_xor(v, 16);
        v += __shfl_xor(v, 32);
        if (lane < 16) red[wv_][nc * 16 + lane] = v;
    }
    __syncthreads();
    if (tid < 64) {
        const float s = red[0][tid] + red[1][tid] + red[2][tid] + red[3][tid];
        partials[(b * 16 + tile) * 64 + tid] = s;
    }
}

// ---------------- Kernel 2: gating finalize (feats -> heads -> weights) --------
__global__ void gate_finalize_kernel(
    const float* __restrict__ partials,
    const float* __restrict__ Wc, const float* __restrict__ bc,
    const float* __restrict__ Wp, const float* __restrict__ bp,
    int* __restrict__ gidx, float* __restrict__ gw)
{
    const int b = threadIdx.x;   // 64 threads
    float f[64];
    #pragma unroll
    for (int g = 0; g < 64; ++g) f[g] = 0.f;
    const float* pb = partials + b * 1024;   // 16 tiles x 64 gf
    #pragma unroll
    for (int t = 0; t < 16; ++t)
        #pragma unroll
        for (int g4 = 0; g4 < 16; ++g4) {
            const float4 v = *(const float4*)&pb[t * 64 + (g4 << 2)];
            f[(g4 << 2) + 0] += v.x;
            f[(g4 << 2) + 1] += v.y;
            f[(g4 << 2) + 2] += v.z;
            f[(g4 << 2) + 3] += v.w;
        }
    #pragma unroll
    for (int g = 0; g < 64; ++g) f[g] *= (1.0f / 4096.0f);

    float cl[6], pl[2];
    #pragma unroll
    for (int j = 0; j < 6; ++j) {
        float s = bc[j];
        #pragma unroll
        for (int g = 0; g < 64; ++g) s += f[g] * Wc[j * 64 + g];
        cl[j] = s;
    }
    #pragma unroll
    for (int j = 0; j < 2; ++j) {
        float s = bp[j];
        #pragma unroll
        for (int g = 0; g < 64; ++g) s += f[g] * Wp[j * 64 + g];
        pl[j] = s;
    }
    const float pm = fmaxf(pl[0], pl[1]);
    const float e0 = expf(pl[0] - pm), e1 = expf(pl[1] - pm);
    const int   pi = (pl[1] > pl[0]) ? 1 : 0;
    const float pv = fmaxf(e0, e1) / (e0 + e1);
    float cm = cl[0];
    #pragma unroll
    for (int j = 1; j < 6; ++j) cm = fmaxf(cm, cl[j]);
    float es = 0.f, ce[6];
    #pragma unroll
    for (int j = 0; j < 6; ++j) { ce[j] = expf(cl[j] - cm); es += ce[j]; }
    int ci = 0; float cbest = cl[0];
    #pragma unroll
    for (int j = 1; j < 6; ++j) if (cl[j] > cbest) { cbest = cl[j]; ci = j; }
    const float cv = ce[ci] / es;

    const float wp = 0.3f * pv;
    const float wc = 0.7f * cv;
    const float tot = wp + wc + 1e-8f;
    gidx[b]      = pi;
    gidx[64 + b] = ci + 2;
    gw[b]        = wp / tot;
    gw[64 + b]   = wc / tot;
}

// ---------------- Kernel 3: fused two-expert conv3x3 -> relu -> conv3x3 -------
// r3-verbatim (measured 82-84 us). grid (64 tiles of 32x32, 64 batch), 256 thr.
__global__ __launch_bounds__(256) void expert_kernel(
    const float* __restrict__ x,
    const float* __restrict__ We1, const float* __restrict__ be1,
    const float* __restrict__ We2, const float* __restrict__ be2,
    const int* __restrict__ gidx, const float* __restrict__ gw,
    float* __restrict__ out)
{
    __shared__ float xs[36 * 40];                             // fp32 x tile + halo2
    __shared__ __align__(16) unsigned short hs[8 * 34 * 36];  // bf16 h, stride 36

    const int tile = blockIdx.x;
    const int b    = blockIdx.y;
    const int ty = tile >> 3, tx = tile & 7;
    const int y0 = ty * 32, x0 = tx * 32;
    const int tid = threadIdx.x;
    const bool interior = (ty != 0) && (ty != 7) && (tx != 0) && (tx != 7);

    const float* xb = x + (size_t)b * (IMG * IMG);
    if (interior) {
        for (int i = tid; i < 36 * 40; i += 256) {
            int r = i / 40, c = i - r * 40;
            xs[i] = xb[(y0 - 2 + r) * IMG + (x0 - 2 + c)];
        }
    } else {
        for (int i = tid; i < 36 * 40; i += 256) {
            int r = i / 40, c = i - r * 40;
            float v = 0.f;
            if (c < 36) {
                int gy = y0 - 2 + r, gx = x0 - 2 + c;
                if (gy >= 0 && gy < IMG && gx >= 0 && gx < IMG) v = xb[gy * IMG + gx];
            }
            xs[i] = v;
        }
    }

    const int ep = __builtin_amdgcn_readfirstlane(gidx[b]);
    const int ec = __builtin_amdgcn_readfirstlane(gidx[64 + b]);
    const float wA = __uint_as_float(__builtin_amdgcn_readfirstlane(__float_as_uint(gw[b])));
    const float wB = __uint_as_float(__builtin_amdgcn_readfirstlane(__float_as_uint(gw[64 + b])));

    const int r_ = tid >> 3;          // 0..31 output row
    const int c0 = (tid & 7) << 2;    // output col group (4 cols)
    const int c1ch   = tid >> 5;      // conv1: channel 0..7
    const int lane32 = tid & 31;

    float oacc0 = 0.f, oacc1 = 0.f, oacc2 = 0.f, oacc3 = 0.f;

    __syncthreads();

    for (int ei = 0; ei < 2; ++ei) {
        const int   e   = ei ? ec : ep;
        const float wgt = ei ? wB : wA;

        float w1r[9];
        const float* w1p = We1 + e * 72 + c1ch * 9;
        #pragma unroll
        for (int k = 0; k < 9; ++k) w1r[k] = w1p[k];
        const float b1r = be1[e * 8 + c1ch];

        if (ei) __syncthreads();   // prev conv2 reads done before hs overwrite

        // ---- conv1: h = relu(conv(x) + b1) in bf16, zero outside image ----
        if (interior) {
            for (int j = lane32; j < 306; j += 32) {
                const int hy = j / 9;
                const int cb = (j - hy * 9) << 2;     // 0,4,...,32
                float a0 = b1r, a1 = b1r, a2 = b1r, a3 = b1r;
                #pragma unroll
                for (int ky = 0; ky < 3; ++ky) {
                    const float* xr = &xs[(hy + ky) * 40 + cb];
                    const float2 xa  = *(const float2*)(xr);
                    const float2 xb2 = *(const float2*)(xr + 2);
                    const float2 xc2 = *(const float2*)(xr + 4);
                    const float wa = w1r[ky * 3 + 0], wb = w1r[ky * 3 + 1], wcc = w1r[ky * 3 + 2];
                    a0 += wa * xa.x  + wb * xa.y  + wcc * xb2.x;
                    a1 += wa * xa.y  + wb * xb2.x + wcc * xb2.y;
                    a2 += wa * xb2.x + wb * xb2.y + wcc * xc2.x;
                    a3 += wa * xb2.y + wb * xc2.x + wcc * xc2.y;
                }
                const unsigned int lo = bf16u(fmaxf(a0, 0.f)) | (bf16u(fmaxf(a1, 0.f)) << 16);
                const unsigned int hi = bf16u(fmaxf(a2, 0.f)) | (bf16u(fmaxf(a3, 0.f)) << 16);
                unsigned short* hp = &hs[c1ch * 1224 + hy * 36 + cb];
                if (cb < 32) *(uint2*)hp = make_uint2(lo, hi);
                else         *(unsigned int*)hp = lo;
            }
        } else {
            for (int j = lane32; j < 306; j += 32) {
                const int hy = j / 9;
                const int cb = (j - hy * 9) << 2;
                float a0 = b1r, a1 = b1r, a2 = b1r, a3 = b1r;
                #pragma unroll
                for (int ky = 0; ky < 3; ++ky) {
                    const float* xr = &xs[(hy + ky) * 40 + cb];
                    const float2 xa  = *(const float2*)(xr);
                    const float2 xb2 = *(const float2*)(xr + 2);
                    const float2 xc2 = *(const float2*)(xr + 4);
                    const float wa = w1r[ky * 3 + 0], wb = w1r[ky * 3 + 1], wcc = w1r[ky * 3 + 2];
                    a0 += wa * xa.x  + wb * xa.y  + wcc * xb2.x;
                    a1 += wa * xa.y  + wb * xb2.x + wcc * xb2.y;
                    a2 += wa * xb2.x + wb * xb2.y + wcc * xc2.x;
                    a3 += wa * xb2.y + wb * xc2.x + wcc * xc2.y;
                }
                const int gy = y0 - 1 + hy;
                const int gx = x0 - 1 + cb;
                const bool rowok = (gy >= 0) && (gy < IMG);
                const float h0 = (rowok && gx >= 0 && gx < IMG) ? fmaxf(a0, 0.f) : 0.f;
                const float h1 = (rowok && (gx + 1) < IMG)      ? fmaxf(a1, 0.f) : 0.f;
                const float h2 = (rowok && (gx + 2) < IMG)      ? fmaxf(a2, 0.f) : 0.f;
                const float h3 = (rowok && (gx + 3) < IMG)      ? fmaxf(a3, 0.f) : 0.f;
                const unsigned int lo = bf16u(h0) | (bf16u(h1) << 16);
                const unsigned int hi = bf16u(h2) | (bf16u(h3) << 16);
                unsigned short* hp = &hs[c1ch * 1224 + hy * 36 + cb];
                if (cb < 32) *(uint2*)hp = make_uint2(lo, hi);
                else         *(unsigned int*)hp = lo;
            }
        }
        __syncthreads();

        // ---- conv2: y = conv(h) + b2, accumulate with gate weight ----
        float a0 = 0.f, a1 = 0.f, a2 = 0.f, a3 = 0.f;
        #pragma unroll
        for (int ch = 0; ch < 8; ++ch) {
            const float* w2p = We2 + e * 72 + ch * 9;   // e uniform -> s_load
            float w2r[9];
            #pragma unroll
            for (int k = 0; k < 9; ++k) w2r[k] = w2p[k];
            #pragma unroll
            for (int ky = 0; ky < 3; ++ky) {
                const unsigned short* hp = &hs[ch * 1224 + (r_ + ky) * 36 + c0];
                const uint2 q4 = *(const uint2*)hp;
                const unsigned int q2 = *(const unsigned int*)(hp + 4);
                const float h0 = bflo(q4.x), h1 = bfhi(q4.x);
                const float h2 = bflo(q4.y), h3 = bfhi(q4.y);
                const float h4 = bflo(q2),   h5 = bfhi(q2);
                const float wa = w2r[ky * 3], wb = w2r[ky * 3 + 1], wcx = w2r[ky * 3 + 2];
                a0 += wa * h0 + wb * h1 + wcx * h2;
                a1 += wa * h1 + wb * h2 + wcx * h3;
                a2 += wa * h2 + wb * h3 + wcx * h4;
                a3 += wa * h3 + wb * h4 + wcx * h5;
            }
        }
        const float b2v = be2[e];
        oacc0 += wgt * (a0 + b2v);
        oacc1 += wgt * (a1 + b2v);
        oacc2 += wgt * (a2 + b2v);
        oacc3 += wgt * (a3 + b2v);
    }

    const float4 o4 = make_float4(oacc0, oacc1, oacc2, oacc3);
    *(float4*)&out[(size_t)b * (IMG * IMG) + (y0 + r_) * IMG + (x0 + c0)] = o4;
}

extern "C" void kernel_launch(void* const* d_in, const int* in_sizes, int n_in,
                              void* d_out, int out_size, void* d_ws, size_t ws_size,
                              hipStream_t stream) {
    const float* x   = (const float*)d_in[0];
    const float* Wg  = (const float*)d_in[1];
    const float* Wc  = (const float*)d_in[2];
    const float* bc  = (const float*)d_in[3];
    const float* Wp  = (const float*)d_in[4];
    const float* bp  = (const float*)d_in[5];
    const float* We1 = (const float*)d_in[6];
    const float* be1 = (const float*)d_in[7];
    const float* We2 = (const float*)d_in[8];
    const float* be2 = (const float*)d_in[9];
    float* out = (float*)d_out;

    float* partials = (float*)d_ws;                              // 256 KB
    int*   gidx     = (int*)((char*)d_ws + 262144);              // 512 B
    float* gw       = (float*)((char*)d_ws + 262656);            // 512 B
    short* bhi      = (short*)((char*)d_ws + 263168);            // 8 KB
    short* blo      = (short*)((char*)d_ws + 271360);            // 8 KB

    gate_prep_kernel<<<dim3(1), dim3(64), 0, stream>>>(Wg, bhi, blo);
    gate_mfma_kernel<<<dim3(16, 64), dim3(256), 0, stream>>>(x, bhi, blo, partials);
    gate_finalize_kernel<<<dim3(1), dim3(64), 0, stream>>>(partials, Wc, bc, Wp, bp, gidx, gw);
    expert_kernel<<<dim3(64, 64), dim3(256), 0, stream>>>(x, We1, be1, We2, be2, gidx, gw, out);
}

// Round 7
// 105.459 us; speedup vs baseline: 1.1687x; 1.1040x over previous
//
#include <hip/hip_runtime.h>
#include <hip/hip_bf16.h>
#include <math.h>

#define IMG 256

typedef __attribute__((ext_vector_type(4))) short short4v;
typedef __attribute__((ext_vector_type(8))) short short8v;
typedef __attribute__((ext_vector_type(4))) float f32x4;
typedef __attribute__((ext_vector_type(2))) float v2f;

__device__ __forceinline__ short bf16s(float f) {
    __hip_bfloat16 h = __float2bfloat16(f);
    short s; __builtin_memcpy(&s, &h, 2); return s;
}
__device__ __forceinline__ unsigned int bf16u(float f) {
    return (unsigned int)(unsigned short)bf16s(f);
}
__device__ __forceinline__ float bflo(unsigned int v) { return __uint_as_float(v << 16); }
__device__ __forceinline__ float bfhi(unsigned int v) { return __uint_as_float(v & 0xffff0000u); }

// ---------------- Kernel 0: pack gating W into MFMA B-fragment layout ---------
__global__ void gate_prep_kernel(const float* __restrict__ Wg,
                                 short* __restrict__ bhi, short* __restrict__ blo)
{
    const int l = threadIdx.x;          // 0..63
    const int kb = l >> 4, m = l & 15;
    #pragma unroll
    for (int s = 0; s < 2; ++s) {
        const int ky = kb + 4 * s;      // 0..7 (7 = zero pad row)
        #pragma unroll
        for (int nc = 0; nc < 4; ++nc) {
            const int gf = nc * 16 + m;
            #pragma unroll
            for (int j = 0; j < 8; ++j) {   // kx (7 = zero pad col)
                float wv = 0.f;
                if (j < 7 && ky < 7) wv = Wg[gf * 49 + ky * 7 + j];
                const short hi = bf16s(wv);
                const float hif = __uint_as_float(((unsigned int)(unsigned short)hi) << 16);
                const int idx = ((s * 4 + nc) * 64 + l) * 8 + j;
                bhi[idx] = hi;
                blo[idx] = bf16s(wv - hif);
            }
        }
    }
}

// ---------------- Kernel 1: gating conv 7x7 s4 + relu + partial sums via MFMA --
// grid (16 tiles = 8 row x 2 col, 64 batch), 256 threads
__global__ __launch_bounds__(256) void gate_mfma_kernel(
    const float* __restrict__ x,
    const short* __restrict__ bhi, const short* __restrict__ blo,
    float* __restrict__ partials)
{
    __shared__ short xs[36 * 136];
    __shared__ float red[4][64];

    const int tile = blockIdx.x;       // 0..15
    const int rt = tile >> 1, ct = tile & 1;
    const int b   = blockIdx.y;
    const int tid = threadIdx.x;

    // ---- x staging, vectorized float4 ----
    const float* xb = x + (size_t)b * (IMG * IMG);
    const int gy0 = rt * 32 - 1;
    {
        const int qx = tid & 31;       // quad -> xs cols 1+4qx .. 4+4qx
        const int rb = tid >> 5;       // 0..7
        #pragma unroll
        for (int t = 0; t < 5; ++t) {
            const int r = rb + 8 * t;
            if (r < 36) {
                const int gy = gy0 + r;
                float4 v = make_float4(0.f, 0.f, 0.f, 0.f);
                if (gy >= 0 && gy < IMG)
                    v = *(const float4*)&xb[gy * IMG + 128 * ct + 4 * qx];
                short* p = &xs[r * 136 + 4 * qx + 1];
                p[0] = bf16s(v.x); p[1] = bf16s(v.y); p[2] = bf16s(v.z); p[3] = bf16s(v.w);
            }
        }
    }
    if (tid < 36) {                    // col 0 (gx = 128ct-1)
        const int r = tid, gy = gy0 + r;
        float v = 0.f;
        if (gy >= 0 && gy < IMG && ct == 1) v = xb[gy * IMG + 127];
        xs[r * 136] = bf16s(v);
    }
    if (tid < 36) {                    // cols 129..132 (gx = 128ct+128..131)
        const int r = tid, gy = gy0 + r;
        float4 v = make_float4(0.f, 0.f, 0.f, 0.f);
        if (gy >= 0 && gy < IMG && ct == 0)
            v = *(const float4*)&xb[gy * IMG + 128];
        short* p = &xs[r * 136 + 129];
        p[0] = bf16s(v.x); p[1] = bf16s(v.y); p[2] = bf16s(v.z); p[3] = bf16s(v.w);
    }

    const int lane = tid & 63;
    const int wv_  = tid >> 6;   // wave 0..3
    const int m    = lane & 15;
    const int kb   = lane >> 4;  // 0..3

    // ---- B fragments: coalesced 16B global loads (L2-resident broadcast) ----
    short8v Bhi[2][4], Blo[2][4];
    #pragma unroll
    for (int s = 0; s < 2; ++s)
        #pragma unroll
        for (int nc = 0; nc < 4; ++nc) {
            const int base = ((s * 4 + nc) * 64 + lane) * 8;
            Bhi[s][nc] = *(const short8v*)&bhi[base];
            Blo[s][nc] = *(const short8v*)&blo[base];
        }

    __syncthreads();

    float rsum[4] = {0.f, 0.f, 0.f, 0.f};
    const f32x4 zero4 = {0.f, 0.f, 0.f, 0.f};

    #pragma unroll 1
    for (int i = 0; i < 4; ++i) {            // 4 chunks per wave, 16 per block
        const int chunk = wv_ * 4 + i;
        const int r = chunk >> 1, q = chunk & 1;
        short8v A[2];
        #pragma unroll
        for (int s = 0; s < 2; ++s) {
            const int row = 4 * r + kb + 4 * s;
            const short4v* p = (const short4v*)&xs[row * 136 + 64 * q + 4 * m];
            const short4v lo4 = p[0], hi4 = p[1];
            A[s] = __builtin_shufflevector(lo4, hi4, 0, 1, 2, 3, 4, 5, 6, 7);
        }
        #pragma unroll
        for (int nc = 0; nc < 4; ++nc) {
            f32x4 z = __builtin_amdgcn_mfma_f32_16x16x32_bf16(A[0], Bhi[0][nc], zero4, 0, 0, 0);
            z = __builtin_amdgcn_mfma_f32_16x16x32_bf16(A[1], Bhi[1][nc], z, 0, 0, 0);
            z = __builtin_amdgcn_mfma_f32_16x16x32_bf16(A[0], Blo[0][nc], z, 0, 0, 0);
            z = __builtin_amdgcn_mfma_f32_16x16x32_bf16(A[1], Blo[1][nc], z, 0, 0, 0);
            rsum[nc] += fmaxf(z[0], 0.f) + fmaxf(z[1], 0.f) + fmaxf(z[2], 0.f) + fmaxf(z[3], 0.f);
        }
    }

    #pragma unroll
    for (int nc = 0; nc < 4; ++nc) {
        float v = rsum[nc];
        v += __shfl_xor(v, 16);
        v += __shfl_xor(v, 32);
        if (lane < 16) red[wv_][nc * 16 + lane] = v;
    }
    __syncthreads();
    if (tid < 64) {
        const float s = red[0][tid] + red[1][tid] + red[2][tid] + red[3][tid];
        partials[(b * 16 + tile) * 64 + tid] = s;
    }
}

// ---------------- Kernel 2: gating finalize, 256 thr (4-way tile split) -------
__global__ __launch_bounds__(256) void gate_finalize_kernel(
    const float* __restrict__ partials,
    const float* __restrict__ Wc, const float* __restrict__ bc,
    const float* __restrict__ Wp, const float* __restrict__ bp,
    int* __restrict__ gidx, float* __restrict__ gw)
{
    __shared__ float lsh[4][64][8];
    const int t = threadIdx.x;
    const int b = t & 63, part = t >> 6;   // part: 4 tiles each

    float f[64];
    #pragma unroll
    for (int g = 0; g < 64; ++g) f[g] = 0.f;
    const float* pb = partials + b * 1024 + part * 256;   // 4 tiles x 64 gf
    #pragma unroll
    for (int tt = 0; tt < 4; ++tt)
        #pragma unroll
        for (int g4 = 0; g4 < 16; ++g4) {
            const float4 v = *(const float4*)&pb[tt * 64 + (g4 << 2)];
            f[(g4 << 2) + 0] += v.x;
            f[(g4 << 2) + 1] += v.y;
            f[(g4 << 2) + 2] += v.z;
            f[(g4 << 2) + 3] += v.w;
        }
    #pragma unroll
    for (int g = 0; g < 64; ++g) f[g] *= (1.0f / 4096.0f);

    // partial logits (bias added after combine)
    #pragma unroll
    for (int j = 0; j < 6; ++j) {
        float s = 0.f;
        #pragma unroll
        for (int g = 0; g < 64; ++g) s += f[g] * Wc[j * 64 + g];
        lsh[part][b][j] = s;
    }
    #pragma unroll
    for (int j = 0; j < 2; ++j) {
        float s = 0.f;
        #pragma unroll
        for (int g = 0; g < 64; ++g) s += f[g] * Wp[j * 64 + g];
        lsh[part][b][6 + j] = s;
    }
    __syncthreads();

    if (t < 64) {
        float cl[6], pl[2];
        #pragma unroll
        for (int j = 0; j < 6; ++j)
            cl[j] = bc[j] + lsh[0][t][j] + lsh[1][t][j] + lsh[2][t][j] + lsh[3][t][j];
        #pragma unroll
        for (int j = 0; j < 2; ++j)
            pl[j] = bp[j] + lsh[0][t][6 + j] + lsh[1][t][6 + j] + lsh[2][t][6 + j] + lsh[3][t][6 + j];

        const float pm = fmaxf(pl[0], pl[1]);
        const float e0 = expf(pl[0] - pm), e1 = expf(pl[1] - pm);
        const int   pi = (pl[1] > pl[0]) ? 1 : 0;
        const float pv = fmaxf(e0, e1) / (e0 + e1);
        float cm = cl[0];
        #pragma unroll
        for (int j = 1; j < 6; ++j) cm = fmaxf(cm, cl[j]);
        float es = 0.f, ce[6];
        #pragma unroll
        for (int j = 0; j < 6; ++j) { ce[j] = expf(cl[j] - cm); es += ce[j]; }
        int ci = 0; float cbest = cl[0];
        #pragma unroll
        for (int j = 1; j < 6; ++j) if (cl[j] > cbest) { cbest = cl[j]; ci = j; }
        const float cv = ce[ci] / es;

        const float wp = 0.3f * pv;
        const float wc = 0.7f * cv;
        const float tot = wp + wc + 1e-8f;
        gidx[t]      = pi;
        gidx[64 + t] = ci + 2;
        gw[t]        = wp / tot;
        gw[64 + t]   = wc / tot;
    }
}

// ---------------- Kernel 3: fused two-expert conv3x3 -> relu -> conv3x3 -------
// r3 structure; inner loops use v2f (v_pk_fma_f32) pairs. Same op order ->
// bit-identical to r3. grid (64 tiles of 32x32, 64 batch), 256 threads.
__global__ __launch_bounds__(256) void expert_kernel(
    const float* __restrict__ x,
    const float* __restrict__ We1, const float* __restrict__ be1,
    const float* __restrict__ We2, const float* __restrict__ be2,
    const int* __restrict__ gidx, const float* __restrict__ gw,
    float* __restrict__ out)
{
    __shared__ float xs[36 * 40];                             // fp32 x tile + halo2
    __shared__ __align__(16) unsigned short hs[8 * 34 * 36];  // bf16 h, stride 36

    const int tile = blockIdx.x;
    const int b    = blockIdx.y;
    const int ty = tile >> 3, tx = tile & 7;
    const int y0 = ty * 32, x0 = tx * 32;
    const int tid = threadIdx.x;
    const bool interior = (ty != 0) && (ty != 7) && (tx != 0) && (tx != 7);

    const float* xb = x + (size_t)b * (IMG * IMG);
    if (interior) {
        for (int i = tid; i < 36 * 40; i += 256) {
            int r = i / 40, c = i - r * 40;
            xs[i] = xb[(y0 - 2 + r) * IMG + (x0 - 2 + c)];
        }
    } else {
        for (int i = tid; i < 36 * 40; i += 256) {
            int r = i / 40, c = i - r * 40;
            float v = 0.f;
            if (c < 36) {
                int gy = y0 - 2 + r, gx = x0 - 2 + c;
                if (gy >= 0 && gy < IMG && gx >= 0 && gx < IMG) v = xb[gy * IMG + gx];
            }
            xs[i] = v;
        }
    }

    const int ep = __builtin_amdgcn_readfirstlane(gidx[b]);
    const int ec = __builtin_amdgcn_readfirstlane(gidx[64 + b]);
    const float wA = __uint_as_float(__builtin_amdgcn_readfirstlane(__float_as_uint(gw[b])));
    const float wB = __uint_as_float(__builtin_amdgcn_readfirstlane(__float_as_uint(gw[64 + b])));

    const int r_ = tid >> 3;          // 0..31 output row
    const int c0 = (tid & 7) << 2;    // output col group (4 cols)
    const int c1ch   = tid >> 5;      // conv1: channel 0..7
    const int lane32 = tid & 31;

    v2f oacc01 = {0.f, 0.f}, oacc23 = {0.f, 0.f};

    __syncthreads();

    for (int ei = 0; ei < 2; ++ei) {
        const int   e   = ei ? ec : ep;
        const float wgt = ei ? wB : wA;

        float w1r[9];
        const float* w1p = We1 + e * 72 + c1ch * 9;
        #pragma unroll
        for (int k = 0; k < 9; ++k) w1r[k] = w1p[k];
        const float b1r = be1[e * 8 + c1ch];

        if (ei) __syncthreads();   // prev conv2 reads done before hs overwrite

        // ---- conv1: h = relu(conv(x) + b1) in bf16, zero outside image ----
        if (interior) {
            for (int j = lane32; j < 306; j += 32) {
                const int hy = j / 9;
                const int cb = (j - hy * 9) << 2;     // 0,4,...,32
                v2f a01 = {b1r, b1r}, a23 = {b1r, b1r};
                #pragma unroll
                for (int ky = 0; ky < 3; ++ky) {
                    const float* xr = &xs[(hy + ky) * 40 + cb];
                    const v2f P01 = *(const v2f*)(xr);
                    const v2f P23 = *(const v2f*)(xr + 2);
                    const v2f P45 = *(const v2f*)(xr + 4);
                    const v2f P12 = {P01.y, P23.x};
                    const v2f P34 = {P23.y, P45.x};
                    const float wa = w1r[ky * 3 + 0], wb = w1r[ky * 3 + 1], wcc = w1r[ky * 3 + 2];
                    const v2f wa2 = {wa, wa}, wb2 = {wb, wb}, wc2 = {wcc, wcc};
                    a01 = wa2 * P01 + a01;
                    a01 = wb2 * P12 + a01;
                    a01 = wc2 * P23 + a01;
                    a23 = wa2 * P23 + a23;
                    a23 = wb2 * P34 + a23;
                    a23 = wc2 * P45 + a23;
                }
                const unsigned int lo = bf16u(fmaxf(a01.x, 0.f)) | (bf16u(fmaxf(a01.y, 0.f)) << 16);
                const unsigned int hi = bf16u(fmaxf(a23.x, 0.f)) | (bf16u(fmaxf(a23.y, 0.f)) << 16);
                unsigned short* hp = &hs[c1ch * 1224 + hy * 36 + cb];
                if (cb < 32) *(uint2*)hp = make_uint2(lo, hi);
                else         *(unsigned int*)hp = lo;
            }
        } else {
            for (int j = lane32; j < 306; j += 32) {
                const int hy = j / 9;
                const int cb = (j - hy * 9) << 2;
                v2f a01 = {b1r, b1r}, a23 = {b1r, b1r};
                #pragma unroll
                for (int ky = 0; ky < 3; ++ky) {
                    const float* xr = &xs[(hy + ky) * 40 + cb];
                    const v2f P01 = *(const v2f*)(xr);
                    const v2f P23 = *(const v2f*)(xr + 2);
                    const v2f P45 = *(const v2f*)(xr + 4);
                    const v2f P12 = {P01.y, P23.x};
                    const v2f P34 = {P23.y, P45.x};
                    const float wa = w1r[ky * 3 + 0], wb = w1r[ky * 3 + 1], wcc = w1r[ky * 3 + 2];
                    const v2f wa2 = {wa, wa}, wb2 = {wb, wb}, wc2 = {wcc, wcc};
                    a01 = wa2 * P01 + a01;
                    a01 = wb2 * P12 + a01;
                    a01 = wc2 * P23 + a01;
                    a23 = wa2 * P23 + a23;
                    a23 = wb2 * P34 + a23;
                    a23 = wc2 * P45 + a23;
                }
                const int gy = y0 - 1 + hy;
                const int gx = x0 - 1 + cb;
                const bool rowok = (gy >= 0) && (gy < IMG);
                const float h0 = (rowok && gx >= 0 && gx < IMG) ? fmaxf(a01.x, 0.f) : 0.f;
                const float h1 = (rowok && (gx + 1) < IMG)      ? fmaxf(a01.y, 0.f) : 0.f;
                const float h2 = (rowok && (gx + 2) < IMG)      ? fmaxf(a23.x, 0.f) : 0.f;
                const float h3 = (rowok && (gx + 3) < IMG)      ? fmaxf(a23.y, 0.f) : 0.f;
                const unsigned int lo = bf16u(h0) | (bf16u(h1) << 16);
                const unsigned int hi = bf16u(h2) | (bf16u(h3) << 16);
                unsigned short* hp = &hs[c1ch * 1224 + hy * 36 + cb];
                if (cb < 32) *(uint2*)hp = make_uint2(lo, hi);
                else         *(unsigned int*)hp = lo;
            }
        }
        __syncthreads();

        // ---- conv2: y = conv(h) + b2, accumulate with gate weight ----
        v2f a01 = {0.f, 0.f}, a23 = {0.f, 0.f};
        #pragma unroll
        for (int ch = 0; ch < 8; ++ch) {
            const float* w2p = We2 + e * 72 + ch * 9;   // e uniform -> s_load
            float w2r[9];
            #pragma unroll
            for (int k = 0; k < 9; ++k) w2r[k] = w2p[k];
            #pragma unroll
            for (int ky = 0; ky < 3; ++ky) {
                const unsigned short* hp = &hs[ch * 1224 + (r_ + ky) * 36 + c0];
                const uint2 q4 = *(const uint2*)hp;
                const unsigned int q2 = *(const unsigned int*)(hp + 4);
                const v2f P01 = {bflo(q4.x), bfhi(q4.x)};
                const v2f P23 = {bflo(q4.y), bfhi(q4.y)};
                const v2f P45 = {bflo(q2),   bfhi(q2)};
                const v2f P12 = {P01.y, P23.x};
                const v2f P34 = {P23.y, P45.x};
                const float wa = w2r[ky * 3], wb = w2r[ky * 3 + 1], wcx = w2r[ky * 3 + 2];
                const v2f wa2 = {wa, wa}, wb2 = {wb, wb}, wc2 = {wcx, wcx};
                a01 = wa2 * P01 + a01;
                a01 = wb2 * P12 + a01;
                a01 = wc2 * P23 + a01;
                a23 = wa2 * P23 + a23;
                a23 = wb2 * P34 + a23;
                a23 = wc2 * P45 + a23;
            }
        }
        const float b2v = be2[e];
        const v2f wgt2 = {wgt, wgt};
        const v2f b2v2 = {b2v, b2v};
        oacc01 = wgt2 * (a01 + b2v2) + oacc01;
        oacc23 = wgt2 * (a23 + b2v2) + oacc23;
    }

    const float4 o4 = make_float4(oacc01.x, oacc01.y, oacc23.x, oacc23.y);
    *(float4*)&out[(size_t)b * (IMG * IMG) + (y0 + r_) * IMG + (x0 + c0)] = o4;
}

extern "C" void kernel_launch(void* const* d_in, const int* in_sizes, int n_in,
                              void* d_out, int out_size, void* d_ws, size_t ws_size,
                              hipStream_t stream) {
    const float* x   = (const float*)d_in[0];
    const float* Wg  = (const float*)d_in[1];
    const float* Wc  = (const float*)d_in[2];
    const float* bc  = (const float*)d_in[3];
    const float* Wp  = (const float*)d_in[4];
    const float* bp  = (const float*)d_in[5];
    const float* We1 = (const float*)d_in[6];
    const float* be1 = (const float*)d_in[7];
    const float* We2 = (const float*)d_in[8];
    const float* be2 = (const float*)d_in[9];
    float* out = (float*)d_out;

    float* partials = (float*)d_ws;                              // 256 KB
    int*   gidx     = (int*)((char*)d_ws + 262144);              // 512 B
    float* gw       = (float*)((char*)d_ws + 262656);            // 512 B
    short* bhi      = (short*)((char*)d_ws + 263168);            // 8 KB
    short* blo      = (short*)((char*)d_ws + 271360);            // 8 KB

    gate_prep_kernel<<<dim3(1), dim3(64), 0, stream>>>(Wg, bhi, blo);
    gate_mfma_kernel<<<dim3(16, 64), dim3(256), 0, stream>>>(x, bhi, blo, partials);
    gate_finalize_kernel<<<dim3(1), dim3(256), 0, stream>>>(partials, Wc, bc, Wp, bp, gidx, gw);
    expert_kernel<<<dim3(64, 64), dim3(256), 0, stream>>>(x, We1, be1, We2, be2, gidx, gw, out);
}

// Round 9
// 98.145 us; speedup vs baseline: 1.2558x; 1.0745x over previous
//
#include <hip/hip_runtime.h>
#include <hip/hip_bf16.h>
#include <math.h>

#define IMG 256

typedef __attribute__((ext_vector_type(4))) short short4v;
typedef __attribute__((ext_vector_type(8))) short short8v;
typedef __attribute__((ext_vector_type(4))) float f32x4;
typedef __attribute__((ext_vector_type(2))) float v2f;
typedef _Float16 half2v __attribute__((ext_vector_type(2)));

__device__ __forceinline__ short bf16s(float f) {
    __hip_bfloat16 h = __float2bfloat16(f);
    short s; __builtin_memcpy(&s, &h, 2); return s;
}
__device__ __forceinline__ half2v h2bits(unsigned int u) {
    half2v h; __builtin_memcpy(&h, &u, 4); return h;
}
template <typename T>
__device__ __forceinline__ unsigned int bits4(T v) {
    static_assert(sizeof(T) == 4, "bits4 needs 4-byte type");
    unsigned int u; __builtin_memcpy(&u, &v, 4); return u;
}
__device__ __forceinline__ unsigned int h16b(float f) {
    _Float16 h = (_Float16)f;          // RNE
    unsigned short s; __builtin_memcpy(&s, &h, 2); return (unsigned int)s;
}

// ---------------- Kernel 0: prep — gate W MFMA B-frags + expert conv2 w-pairs --
__global__ void gate_prep_kernel(const float* __restrict__ Wg,
                                 const float* __restrict__ We2,
                                 short* __restrict__ bhi, short* __restrict__ blo,
                                 unsigned int* __restrict__ w2pack)
{
    const int l = threadIdx.x;          // 0..63
    const int kb = l >> 4, m = l & 15;
    #pragma unroll
    for (int s = 0; s < 2; ++s) {
        const int ky = kb + 4 * s;      // 0..7 (7 = zero pad row)
        #pragma unroll
        for (int nc = 0; nc < 4; ++nc) {
            const int gf = nc * 16 + m;
            #pragma unroll
            for (int j = 0; j < 8; ++j) {   // kx (7 = zero pad col)
                float wv = 0.f;
                if (j < 7 && ky < 7) wv = Wg[gf * 49 + ky * 7 + j];
                const short hi = bf16s(wv);
                const float hif = __uint_as_float(((unsigned int)(unsigned short)hi) << 16);
                const int idx = ((s * 4 + nc) * 64 + l) * 8 + j;
                bhi[idx] = hi;
                blo[idx] = bf16s(wv - hif);
            }
        }
    }
    // conv2 weight pairs: item i = (e,ch,ky); 4 uints = (wa,wb),(wc,0),(0,wa),(wb,wc)
    for (int i = l; i < 192; i += 64) {
        const int e = i / 24, rem = i - e * 24;
        const int ch = rem / 3, ky = rem - ch * 3;
        const float* wp = We2 + e * 72 + ch * 9 + ky * 3;
        const unsigned int ha = h16b(wp[0]), hb = h16b(wp[1]), hc = h16b(wp[2]);
        w2pack[i * 4 + 0] = ha | (hb << 16);
        w2pack[i * 4 + 1] = hc;
        w2pack[i * 4 + 2] = (ha << 16);
        w2pack[i * 4 + 3] = hb | (hc << 16);
    }
}

// ---------------- Kernel 1: gating conv 7x7 s4 + relu + partial sums via MFMA --
// grid (16 tiles = 8 row x 2 col, 64 batch), 256 threads
__global__ __launch_bounds__(256) void gate_mfma_kernel(
    const float* __restrict__ x,
    const short* __restrict__ bhi, const short* __restrict__ blo,
    float* __restrict__ partials)
{
    __shared__ short xs[36 * 136];
    __shared__ float red[4][64];

    const int tile = blockIdx.x;       // 0..15
    const int rt = tile >> 1, ct = tile & 1;
    const int b   = blockIdx.y;
    const int tid = threadIdx.x;

    // ---- x staging, vectorized float4 ----
    const float* xb = x + (size_t)b * (IMG * IMG);
    const int gy0 = rt * 32 - 1;
    {
        const int qx = tid & 31;       // quad -> xs cols 1+4qx .. 4+4qx
        const int rb = tid >> 5;       // 0..7
        #pragma unroll
        for (int t = 0; t < 5; ++t) {
            const int r = rb + 8 * t;
            if (r < 36) {
                const int gy = gy0 + r;
                float4 v = make_float4(0.f, 0.f, 0.f, 0.f);
                if (gy >= 0 && gy < IMG)
                    v = *(const float4*)&xb[gy * IMG + 128 * ct + 4 * qx];
                short* p = &xs[r * 136 + 4 * qx + 1];
                p[0] = bf16s(v.x); p[1] = bf16s(v.y); p[2] = bf16s(v.z); p[3] = bf16s(v.w);
            }
        }
    }
    if (tid < 36) {                    // col 0 (gx = 128ct-1)
        const int r = tid, gy = gy0 + r;
        float v = 0.f;
        if (gy >= 0 && gy < IMG && ct == 1) v = xb[gy * IMG + 127];
        xs[r * 136] = bf16s(v);
    }
    if (tid < 36) {                    // cols 129..132 (gx = 128ct+128..131)
        const int r = tid, gy = gy0 + r;
        float4 v = make_float4(0.f, 0.f, 0.f, 0.f);
        if (gy >= 0 && gy < IMG && ct == 0)
            v = *(const float4*)&xb[gy * IMG + 128];
        short* p = &xs[r * 136 + 129];
        p[0] = bf16s(v.x); p[1] = bf16s(v.y); p[2] = bf16s(v.z); p[3] = bf16s(v.w);
    }

    const int lane = tid & 63;
    const int wv_  = tid >> 6;   // wave 0..3
    const int m    = lane & 15;
    const int kb   = lane >> 4;  // 0..3

    // ---- B fragments: coalesced 16B global loads (L2-resident broadcast) ----
    short8v Bhi[2][4], Blo[2][4];
    #pragma unroll
    for (int s = 0; s < 2; ++s)
        #pragma unroll
        for (int nc = 0; nc < 4; ++nc) {
            const int base = ((s * 4 + nc) * 64 + lane) * 8;
            Bhi[s][nc] = *(const short8v*)&bhi[base];
            Blo[s][nc] = *(const short8v*)&blo[base];
        }

    __syncthreads();

    float rsum[4] = {0.f, 0.f, 0.f, 0.f};
    const f32x4 zero4 = {0.f, 0.f, 0.f, 0.f};

    #pragma unroll 1
    for (int i = 0; i < 4; ++i) {            // 4 chunks per wave, 16 per block
        const int chunk = wv_ * 4 + i;
        const int r = chunk >> 1, q = chunk & 1;
        short8v A[2];
        #pragma unroll
        for (int s = 0; s < 2; ++s) {
            const int row = 4 * r + kb + 4 * s;
            const short4v* p = (const short4v*)&xs[row * 136 + 64 * q + 4 * m];
            const short4v lo4 = p[0], hi4 = p[1];
            A[s] = __builtin_shufflevector(lo4, hi4, 0, 1, 2, 3, 4, 5, 6, 7);
        }
        #pragma unroll
        for (int nc = 0; nc < 4; ++nc) {
            f32x4 z = __builtin_amdgcn_mfma_f32_16x16x32_bf16(A[0], Bhi[0][nc], zero4, 0, 0, 0);
            z = __builtin_amdgcn_mfma_f32_16x16x32_bf16(A[1], Bhi[1][nc], z, 0, 0, 0);
            z = __builtin_amdgcn_mfma_f32_16x16x32_bf16(A[0], Blo[0][nc], z, 0, 0, 0);
            z = __builtin_amdgcn_mfma_f32_16x16x32_bf16(A[1], Blo[1][nc], z, 0, 0, 0);
            rsum[nc] += fmaxf(z[0], 0.f) + fmaxf(z[1], 0.f) + fmaxf(z[2], 0.f) + fmaxf(z[3], 0.f);
        }
    }

    #pragma unroll
    for (int nc = 0; nc < 4; ++nc) {
        float v = rsum[nc];
        v += __shfl_xor(v, 16);
        v += __shfl_xor(v, 32);
        if (lane < 16) red[wv_][nc * 16 + lane] = v;
    }
    __syncthreads();
    if (tid < 64) {
        const float s = red[0][tid] + red[1][tid] + red[2][tid] + red[3][tid];
        partials[(b * 16 + tile) * 64 + tid] = s;
    }
}

// ---------------- Kernel 2: gating finalize, 256 thr (4-way tile split) -------
__global__ __launch_bounds__(256) void gate_finalize_kernel(
    const float* __restrict__ partials,
    const float* __restrict__ Wc, const float* __restrict__ bc,
    const float* __restrict__ Wp, const float* __restrict__ bp,
    int* __restrict__ gidx, float* __restrict__ gw)
{
    __shared__ float lsh[4][64][8];
    const int t = threadIdx.x;
    const int b = t & 63, part = t >> 6;   // part: 4 tiles each

    float f[64];
    #pragma unroll
    for (int g = 0; g < 64; ++g) f[g] = 0.f;
    const float* pb = partials + b * 1024 + part * 256;   // 4 tiles x 64 gf
    #pragma unroll
    for (int tt = 0; tt < 4; ++tt)
        #pragma unroll
        for (int g4 = 0; g4 < 16; ++g4) {
            const float4 v = *(const float4*)&pb[tt * 64 + (g4 << 2)];
            f[(g4 << 2) + 0] += v.x;
            f[(g4 << 2) + 1] += v.y;
            f[(g4 << 2) + 2] += v.z;
            f[(g4 << 2) + 3] += v.w;
        }
    #pragma unroll
    for (int g = 0; g < 64; ++g) f[g] *= (1.0f / 4096.0f);

    #pragma unroll
    for (int j = 0; j < 6; ++j) {
        float s = 0.f;
        #pragma unroll
        for (int g = 0; g < 64; ++g) s += f[g] * Wc[j * 64 + g];
        lsh[part][b][j] = s;
    }
    #pragma unroll
    for (int j = 0; j < 2; ++j) {
        float s = 0.f;
        #pragma unroll
        for (int g = 0; g < 64; ++g) s += f[g] * Wp[j * 64 + g];
        lsh[part][b][6 + j] = s;
    }
    __syncthreads();

    if (t < 64) {
        float cl[6], pl[2];
        #pragma unroll
        for (int j = 0; j < 6; ++j)
            cl[j] = bc[j] + lsh[0][t][j] + lsh[1][t][j] + lsh[2][t][j] + lsh[3][t][j];
        #pragma unroll
        for (int j = 0; j < 2; ++j)
            pl[j] = bp[j] + lsh[0][t][6 + j] + lsh[1][t][6 + j] + lsh[2][t][6 + j] + lsh[3][t][6 + j];

        const float pm = fmaxf(pl[0], pl[1]);
        const float e0 = expf(pl[0] - pm), e1 = expf(pl[1] - pm);
        const int   pi = (pl[1] > pl[0]) ? 1 : 0;
        const float pv = fmaxf(e0, e1) / (e0 + e1);
        float cm = cl[0];
        #pragma unroll
        for (int j = 1; j < 6; ++j) cm = fmaxf(cm, cl[j]);
        float es = 0.f, ce[6];
        #pragma unroll
        for (int j = 0; j < 6; ++j) { ce[j] = expf(cl[j] - cm); es += ce[j]; }
        int ci = 0; float cbest = cl[0];
        #pragma unroll
        for (int j = 1; j < 6; ++j) if (cl[j] > cbest) { cbest = cl[j]; ci = j; }
        const float cv = ce[ci] / es;

        const float wp = 0.3f * pv;
        const float wc = 0.7f * cv;
        const float tot = wp + wc + 1e-8f;
        gidx[t]      = pi;
        gidx[64 + t] = ci + 2;
        gw[t]        = wp / tot;
        gw[64 + t]   = wc / tot;
    }
}

// ---------------- Kernel 3: fused two-expert conv3x3 -> relu -> conv3x3 -------
// h in fp16 (cvt_pkrtz); conv2 via v_dot2_f32_f16 on packed pairs.
// grid (64 tiles of 32x32, 64 batch), 256 threads.
__global__ __launch_bounds__(256) void expert_kernel(
    const float* __restrict__ x,
    const float* __restrict__ We1, const float* __restrict__ be1,
    const unsigned int* __restrict__ w2pack, const float* __restrict__ be2,
    const int* __restrict__ gidx, const float* __restrict__ gw,
    float* __restrict__ out)
{
    __shared__ float xs[36 * 40];                             // fp32 x tile + halo2
    __shared__ __align__(16) unsigned short hs[8 * 34 * 36];  // fp16 h, stride 36

    const int tile = blockIdx.x;
    const int b    = blockIdx.y;
    const int ty = tile >> 3, tx = tile & 7;
    const int y0 = ty * 32, x0 = tx * 32;
    const int tid = threadIdx.x;
    const bool interior = (ty != 0) && (ty != 7) && (tx != 0) && (tx != 7);

    const float* xb = x + (size_t)b * (IMG * IMG);
    if (interior) {
        for (int i = tid; i < 36 * 40; i += 256) {
            int r = i / 40, c = i - r * 40;
            xs[i] = xb[(y0 - 2 + r) * IMG + (x0 - 2 + c)];
        }
    } else {
        for (int i = tid; i < 36 * 40; i += 256) {
            int r = i / 40, c = i - r * 40;
            float v = 0.f;
            if (c < 36) {
                int gy = y0 - 2 + r, gx = x0 - 2 + c;
                if (gy >= 0 && gy < IMG && gx >= 0 && gx < IMG) v = xb[gy * IMG + gx];
            }
            xs[i] = v;
        }
    }

    const int ep = __builtin_amdgcn_readfirstlane(gidx[b]);
    const int ec = __builtin_amdgcn_readfirstlane(gidx[64 + b]);
    const float wA = __uint_as_float(__builtin_amdgcn_readfirstlane(__float_as_uint(gw[b])));
    const float wB = __uint_as_float(__builtin_amdgcn_readfirstlane(__float_as_uint(gw[64 + b])));

    const int r_ = tid >> 3;          // 0..31 output row
    const int c0 = (tid & 7) << 2;    // output col group (4 cols)
    const int c1ch   = tid >> 5;      // conv1: channel 0..7
    const int lane32 = tid & 31;

    float oacc0 = 0.f, oacc1 = 0.f, oacc2 = 0.f, oacc3 = 0.f;

    __syncthreads();

    for (int ei = 0; ei < 2; ++ei) {
        const int   e   = ei ? ec : ep;
        const float wgt = ei ? wB : wA;

        float w1r[9];
        const float* w1p = We1 + e * 72 + c1ch * 9;
        #pragma unroll
        for (int k = 0; k < 9; ++k) w1r[k] = w1p[k];
        const float b1r = be1[e * 8 + c1ch];

        if (ei) __syncthreads();   // prev conv2 reads done before hs overwrite

        // ---- conv1: h = relu(conv(x) + b1) in fp16 (pkrtz), zero outside ----
        if (interior) {
            for (int j = lane32; j < 306; j += 32) {
                const int hy = j / 9;
                const int cb = (j - hy * 9) << 2;     // 0,4,...,32
                v2f a01 = {b1r, b1r}, a23 = {b1r, b1r};
                #pragma unroll
                for (int ky = 0; ky < 3; ++ky) {
                    const float* xr = &xs[(hy + ky) * 40 + cb];
                    const v2f P01 = *(const v2f*)(xr);
                    const v2f P23 = *(const v2f*)(xr + 2);
                    const v2f P45 = *(const v2f*)(xr + 4);
                    const v2f P12 = {P01.y, P23.x};
                    const v2f P34 = {P23.y, P45.x};
                    const float wa = w1r[ky * 3 + 0], wb = w1r[ky * 3 + 1], wcc = w1r[ky * 3 + 2];
                    const v2f wa2 = {wa, wa}, wb2 = {wb, wb}, wc2 = {wcc, wcc};
                    a01 = wa2 * P01 + a01;
                    a01 = wb2 * P12 + a01;
                    a01 = wc2 * P23 + a01;
                    a23 = wa2 * P23 + a23;
                    a23 = wb2 * P34 + a23;
                    a23 = wc2 * P45 + a23;
                }
                const unsigned int lo = bits4(
                    __builtin_amdgcn_cvt_pkrtz(fmaxf(a01.x, 0.f), fmaxf(a01.y, 0.f)));
                const unsigned int hi = bits4(
                    __builtin_amdgcn_cvt_pkrtz(fmaxf(a23.x, 0.f), fmaxf(a23.y, 0.f)));
                unsigned short* hp = &hs[c1ch * 1224 + hy * 36 + cb];
                if (cb < 32) *(uint2*)hp = make_uint2(lo, hi);
                else         *(unsigned int*)hp = lo;
            }
        } else {
            for (int j = lane32; j < 306; j += 32) {
                const int hy = j / 9;
                const int cb = (j - hy * 9) << 2;
                v2f a01 = {b1r, b1r}, a23 = {b1r, b1r};
                #pragma unroll
                for (int ky = 0; ky < 3; ++ky) {
                    const float* xr = &xs[(hy + ky) * 40 + cb];
                    const v2f P01 = *(const v2f*)(xr);
                    const v2f P23 = *(const v2f*)(xr + 2);
                    const v2f P45 = *(const v2f*)(xr + 4);
                    const v2f P12 = {P01.y, P23.x};
                    const v2f P34 = {P23.y, P45.x};
                    const float wa = w1r[ky * 3 + 0], wb = w1r[ky * 3 + 1], wcc = w1r[ky * 3 + 2];
                    const v2f wa2 = {wa, wa}, wb2 = {wb, wb}, wc2 = {wcc, wcc};
                    a01 = wa2 * P01 + a01;
                    a01 = wb2 * P12 + a01;
                    a01 = wc2 * P23 + a01;
                    a23 = wa2 * P23 + a23;
                    a23 = wb2 * P34 + a23;
                    a23 = wc2 * P45 + a23;
                }
                const int gy = y0 - 1 + hy;
                const int gx = x0 - 1 + cb;
                const bool rowok = (gy >= 0) && (gy < IMG);
                const float h0 = (rowok && gx >= 0 && gx < IMG) ? fmaxf(a01.x, 0.f) : 0.f;
                const float h1 = (rowok && (gx + 1) < IMG)      ? fmaxf(a01.y, 0.f) : 0.f;
                const float h2 = (rowok && (gx + 2) < IMG)      ? fmaxf(a23.x, 0.f) : 0.f;
                const float h3 = (rowok && (gx + 3) < IMG)      ? fmaxf(a23.y, 0.f) : 0.f;
                const unsigned int lo = bits4(__builtin_amdgcn_cvt_pkrtz(h0, h1));
                const unsigned int hi = bits4(__builtin_amdgcn_cvt_pkrtz(h2, h3));
                unsigned short* hp = &hs[c1ch * 1224 + hy * 36 + cb];
                if (cb < 32) *(uint2*)hp = make_uint2(lo, hi);
                else         *(unsigned int*)hp = lo;
            }
        }
        __syncthreads();

        // ---- conv2 via v_dot2_f32_f16: y = conv(h) + b2 ----
        float a0 = 0.f, a1 = 0.f, a2 = 0.f, a3 = 0.f;
        #pragma unroll
        for (int ch = 0; ch < 8; ++ch) {
            #pragma unroll
            for (int ky = 0; ky < 3; ++ky) {
                const uint4 wp = *(const uint4*)&w2pack[(((e * 8) + ch) * 3 + ky) * 4]; // s_load
                const unsigned short* hp = &hs[ch * 1224 + (r_ + ky) * 36 + c0];
                const uint2 q4 = *(const uint2*)hp;
                const unsigned int q2 = *(const unsigned int*)(hp + 4);
                const half2v P01 = h2bits(q4.x), P23 = h2bits(q4.y), P45 = h2bits(q2);
                const half2v p0 = h2bits(wp.x), p1 = h2bits(wp.y), p2 = h2bits(wp.z), p3 = h2bits(wp.w);
                a0 = __builtin_amdgcn_fdot2(p0, P01, a0, false);
                a0 = __builtin_amdgcn_fdot2(p1, P23, a0, false);
                a1 = __builtin_amdgcn_fdot2(p2, P01, a1, false);
                a1 = __builtin_amdgcn_fdot2(p3, P23, a1, false);
                a2 = __builtin_amdgcn_fdot2(p0, P23, a2, false);
                a2 = __builtin_amdgcn_fdot2(p1, P45, a2, false);
                a3 = __builtin_amdgcn_fdot2(p2, P23, a3, false);
                a3 = __builtin_amdgcn_fdot2(p3, P45, a3, false);
            }
        }
        const float b2v = be2[e];
        oacc0 += wgt * (a0 + b2v);
        oacc1 += wgt * (a1 + b2v);
        oacc2 += wgt * (a2 + b2v);
        oacc3 += wgt * (a3 + b2v);
    }

    const float4 o4 = make_float4(oacc0, oacc1, oacc2, oacc3);
    *(float4*)&out[(size_t)b * (IMG * IMG) + (y0 + r_) * IMG + (x0 + c0)] = o4;
}

extern "C" void kernel_launch(void* const* d_in, const int* in_sizes, int n_in,
                              void* d_out, int out_size, void* d_ws, size_t ws_size,
                              hipStream_t stream) {
    const float* x   = (const float*)d_in[0];
    const float* Wg  = (const float*)d_in[1];
    const float* Wc  = (const float*)d_in[2];
    const float* bc  = (const float*)d_in[3];
    const float* Wp  = (const float*)d_in[4];
    const float* bp  = (const float*)d_in[5];
    const float* We1 = (const float*)d_in[6];
    const float* be1 = (const float*)d_in[7];
    const float* We2 = (const float*)d_in[8];
    const float* be2 = (const float*)d_in[9];
    float* out = (float*)d_out;

    float*        partials = (float*)d_ws;                        // 256 KB
    int*          gidx     = (int*)((char*)d_ws + 262144);        // 512 B
    float*        gw       = (float*)((char*)d_ws + 262656);      // 512 B
    short*        bhi      = (short*)((char*)d_ws + 263168);      // 8 KB
    short*        blo      = (short*)((char*)d_ws + 271360);      // 8 KB
    unsigned int* w2pack   = (unsigned int*)((char*)d_ws + 279552); // 3 KB

    gate_prep_kernel<<<dim3(1), dim3(64), 0, stream>>>(Wg, We2, bhi, blo, w2pack);
    gate_mfma_kernel<<<dim3(16, 64), dim3(256), 0, stream>>>(x, bhi, blo, partials);
    gate_finalize_kernel<<<dim3(1), dim3(256), 0, stream>>>(partials, Wc, bc, Wp, bp, gidx, gw);
    expert_kernel<<<dim3(64, 64), dim3(256), 0, stream>>>(x, We1, be1, w2pack, be2, gidx, gw, out);
}

// Round 10
// 95.744 us; speedup vs baseline: 1.2873x; 1.0251x over previous
//
#include <hip/hip_runtime.h>
#include <hip/hip_bf16.h>
#include <math.h>

#define IMG 256

typedef __attribute__((ext_vector_type(4))) short short4v;
typedef __attribute__((ext_vector_type(8))) short short8v;
typedef __attribute__((ext_vector_type(4))) float f32x4;
typedef __attribute__((ext_vector_type(2))) float v2f;
typedef _Float16 half2v __attribute__((ext_vector_type(2)));

__device__ __forceinline__ short bf16s(float f) {
    __hip_bfloat16 h = __float2bfloat16(f);
    short s; __builtin_memcpy(&s, &h, 2); return s;
}
__device__ __forceinline__ half2v h2bits(unsigned int u) {
    half2v h; __builtin_memcpy(&h, &u, 4); return h;
}
template <typename T>
__device__ __forceinline__ unsigned int bits4(T v) {
    static_assert(sizeof(T) == 4, "bits4 needs 4-byte type");
    unsigned int u; __builtin_memcpy(&u, &v, 4); return u;
}
__device__ __forceinline__ unsigned int h16b(float f) {
    _Float16 h = (_Float16)f;          // RNE
    unsigned short s; __builtin_memcpy(&s, &h, 2); return (unsigned int)s;
}

// ---------------- Kernel 0: prep — gate W MFMA B-frags + expert conv2 w-pairs --
__global__ void gate_prep_kernel(const float* __restrict__ Wg,
                                 const float* __restrict__ We2,
                                 short* __restrict__ bhi, short* __restrict__ blo,
                                 unsigned int* __restrict__ w2pack)
{
    const int l = threadIdx.x;          // 0..63
    const int kb = l >> 4, m = l & 15;
    #pragma unroll
    for (int s = 0; s < 2; ++s) {
        const int ky = kb + 4 * s;      // 0..7 (7 = zero pad row)
        #pragma unroll
        for (int nc = 0; nc < 4; ++nc) {
            const int gf = nc * 16 + m;
            #pragma unroll
            for (int j = 0; j < 8; ++j) {   // kx (7 = zero pad col)
                float wv = 0.f;
                if (j < 7 && ky < 7) wv = Wg[gf * 49 + ky * 7 + j];
                const short hi = bf16s(wv);
                const float hif = __uint_as_float(((unsigned int)(unsigned short)hi) << 16);
                const int idx = ((s * 4 + nc) * 64 + l) * 8 + j;
                bhi[idx] = hi;
                blo[idx] = bf16s(wv - hif);
            }
        }
    }
    // conv2 weight pairs: item i = (e,ch,ky); 4 uints = (wa,wb),(wc,0),(0,wa),(wb,wc)
    for (int i = l; i < 192; i += 64) {
        const int e = i / 24, rem = i - e * 24;
        const int ch = rem / 3, ky = rem - ch * 3;
        const float* wp = We2 + e * 72 + ch * 9 + ky * 3;
        const unsigned int ha = h16b(wp[0]), hb = h16b(wp[1]), hc = h16b(wp[2]);
        w2pack[i * 4 + 0] = ha | (hb << 16);
        w2pack[i * 4 + 1] = hc;
        w2pack[i * 4 + 2] = (ha << 16);
        w2pack[i * 4 + 3] = hb | (hc << 16);
    }
}

// ---------------- Kernel 1: gating conv 7x7 s4 + relu + partial sums via MFMA --
// grid (16 tiles = 8 row x 2 col, 64 batch), 256 threads
__global__ __launch_bounds__(256) void gate_mfma_kernel(
    const float* __restrict__ x,
    const short* __restrict__ bhi, const short* __restrict__ blo,
    float* __restrict__ partials)
{
    __shared__ short xs[36 * 136];
    __shared__ float red[4][64];

    const int tile = blockIdx.x;       // 0..15
    const int rt = tile >> 1, ct = tile & 1;
    const int b   = blockIdx.y;
    const int tid = threadIdx.x;

    // ---- x staging, vectorized float4 ----
    const float* xb = x + (size_t)b * (IMG * IMG);
    const int gy0 = rt * 32 - 1;
    {
        const int qx = tid & 31;       // quad -> xs cols 1+4qx .. 4+4qx
        const int rb = tid >> 5;       // 0..7
        #pragma unroll
        for (int t = 0; t < 5; ++t) {
            const int r = rb + 8 * t;
            if (r < 36) {
                const int gy = gy0 + r;
                float4 v = make_float4(0.f, 0.f, 0.f, 0.f);
                if (gy >= 0 && gy < IMG)
                    v = *(const float4*)&xb[gy * IMG + 128 * ct + 4 * qx];
                short* p = &xs[r * 136 + 4 * qx + 1];
                p[0] = bf16s(v.x); p[1] = bf16s(v.y); p[2] = bf16s(v.z); p[3] = bf16s(v.w);
            }
        }
    }
    if (tid < 36) {                    // col 0 (gx = 128ct-1)
        const int r = tid, gy = gy0 + r;
        float v = 0.f;
        if (gy >= 0 && gy < IMG && ct == 1) v = xb[gy * IMG + 127];
        xs[r * 136] = bf16s(v);
    }
    if (tid < 36) {                    // cols 129..132 (gx = 128ct+128..131)
        const int r = tid, gy = gy0 + r;
        float4 v = make_float4(0.f, 0.f, 0.f, 0.f);
        if (gy >= 0 && gy < IMG && ct == 0)
            v = *(const float4*)&xb[gy * IMG + 128];
        short* p = &xs[r * 136 + 129];
        p[0] = bf16s(v.x); p[1] = bf16s(v.y); p[2] = bf16s(v.z); p[3] = bf16s(v.w);
    }

    const int lane = tid & 63;
    const int wv_  = tid >> 6;   // wave 0..3
    const int m    = lane & 15;
    const int kb   = lane >> 4;  // 0..3

    // ---- B fragments: coalesced 16B global loads (L2-resident broadcast) ----
    short8v Bhi[2][4], Blo[2][4];
    #pragma unroll
    for (int s = 0; s < 2; ++s)
        #pragma unroll
        for (int nc = 0; nc < 4; ++nc) {
            const int base = ((s * 4 + nc) * 64 + lane) * 8;
            Bhi[s][nc] = *(const short8v*)&bhi[base];
            Blo[s][nc] = *(const short8v*)&blo[base];
        }

    __syncthreads();

    float rsum[4] = {0.f, 0.f, 0.f, 0.f};
    const f32x4 zero4 = {0.f, 0.f, 0.f, 0.f};

    #pragma unroll 1
    for (int i = 0; i < 4; ++i) {            // 4 chunks per wave, 16 per block
        const int chunk = wv_ * 4 + i;
        const int r = chunk >> 1, q = chunk & 1;
        short8v A[2];
        #pragma unroll
        for (int s = 0; s < 2; ++s) {
            const int row = 4 * r + kb + 4 * s;
            const short4v* p = (const short4v*)&xs[row * 136 + 64 * q + 4 * m];
            const short4v lo4 = p[0], hi4 = p[1];
            A[s] = __builtin_shufflevector(lo4, hi4, 0, 1, 2, 3, 4, 5, 6, 7);
        }
        #pragma unroll
        for (int nc = 0; nc < 4; ++nc) {
            f32x4 z = __builtin_amdgcn_mfma_f32_16x16x32_bf16(A[0], Bhi[0][nc], zero4, 0, 0, 0);
            z = __builtin_amdgcn_mfma_f32_16x16x32_bf16(A[1], Bhi[1][nc], z, 0, 0, 0);
            z = __builtin_amdgcn_mfma_f32_16x16x32_bf16(A[0], Blo[0][nc], z, 0, 0, 0);
            z = __builtin_amdgcn_mfma_f32_16x16x32_bf16(A[1], Blo[1][nc], z, 0, 0, 0);
            rsum[nc] += fmaxf(z[0], 0.f) + fmaxf(z[1], 0.f) + fmaxf(z[2], 0.f) + fmaxf(z[3], 0.f);
        }
    }

    #pragma unroll
    for (int nc = 0; nc < 4; ++nc) {
        float v = rsum[nc];
        v += __shfl_xor(v, 16);
        v += __shfl_xor(v, 32);
        if (lane < 16) red[wv_][nc * 16 + lane] = v;
    }
    __syncthreads();
    if (tid < 64) {
        const float s = red[0][tid] + red[1][tid] + red[2][tid] + red[3][tid];
        partials[(b * 16 + tile) * 64 + tid] = s;
    }
}

// ---------------- Kernel 2: gating finalize, 256 thr (4-way tile split) -------
__global__ __launch_bounds__(256) void gate_finalize_kernel(
    const float* __restrict__ partials,
    const float* __restrict__ Wc, const float* __restrict__ bc,
    const float* __restrict__ Wp, const float* __restrict__ bp,
    int* __restrict__ gidx, float* __restrict__ gw)
{
    __shared__ float lsh[4][64][8];
    const int t = threadIdx.x;
    const int b = t & 63, part = t >> 6;   // part: 4 tiles each

    float f[64];
    #pragma unroll
    for (int g = 0; g < 64; ++g) f[g] = 0.f;
    const float* pb = partials + b * 1024 + part * 256;   // 4 tiles x 64 gf
    #pragma unroll
    for (int tt = 0; tt < 4; ++tt)
        #pragma unroll
        for (int g4 = 0; g4 < 16; ++g4) {
            const float4 v = *(const float4*)&pb[tt * 64 + (g4 << 2)];
            f[(g4 << 2) + 0] += v.x;
            f[(g4 << 2) + 1] += v.y;
            f[(g4 << 2) + 2] += v.z;
            f[(g4 << 2) + 3] += v.w;
        }
    #pragma unroll
    for (int g = 0; g < 64; ++g) f[g] *= (1.0f / 4096.0f);

    #pragma unroll
    for (int j = 0; j < 6; ++j) {
        float s = 0.f;
        #pragma unroll
        for (int g = 0; g < 64; ++g) s += f[g] * Wc[j * 64 + g];
        lsh[part][b][j] = s;
    }
    #pragma unroll
    for (int j = 0; j < 2; ++j) {
        float s = 0.f;
        #pragma unroll
        for (int g = 0; g < 64; ++g) s += f[g] * Wp[j * 64 + g];
        lsh[part][b][6 + j] = s;
    }
    __syncthreads();

    if (t < 64) {
        float cl[6], pl[2];
        #pragma unroll
        for (int j = 0; j < 6; ++j)
            cl[j] = bc[j] + lsh[0][t][j] + lsh[1][t][j] + lsh[2][t][j] + lsh[3][t][j];
        #pragma unroll
        for (int j = 0; j < 2; ++j)
            pl[j] = bp[j] + lsh[0][t][6 + j] + lsh[1][t][6 + j] + lsh[2][t][6 + j] + lsh[3][t][6 + j];

        const float pm = fmaxf(pl[0], pl[1]);
        const float e0 = expf(pl[0] - pm), e1 = expf(pl[1] - pm);
        const int   pi = (pl[1] > pl[0]) ? 1 : 0;
        const float pv = fmaxf(e0, e1) / (e0 + e1);
        float cm = cl[0];
        #pragma unroll
        for (int j = 1; j < 6; ++j) cm = fmaxf(cm, cl[j]);
        float es = 0.f, ce[6];
        #pragma unroll
        for (int j = 0; j < 6; ++j) { ce[j] = expf(cl[j] - cm); es += ce[j]; }
        int ci = 0; float cbest = cl[0];
        #pragma unroll
        for (int j = 1; j < 6; ++j) if (cl[j] > cbest) { cbest = cl[j]; ci = j; }
        const float cv = ce[ci] / es;

        const float wp = 0.3f * pv;
        const float wc = 0.7f * cv;
        const float tot = wp + wc + 1e-8f;
        gidx[t]      = pi;
        gidx[64 + t] = ci + 2;
        gw[t]        = wp / tot;
        gw[64 + t]   = wc / tot;
    }
}

// ---------------- Kernel 3: fused two-expert conv3x3 -> relu -> conv3x3 -------
// conv1: 4x4 output patches (9x9 grid, 3 passes/lane) — halves conv1 LDS reads.
// h in fp16 (cvt_pkrtz); conv2 via v_dot2_f32_f16 on packed pairs.
// grid (64 tiles of 32x32, 64 batch), 256 threads.
__global__ __launch_bounds__(256) void expert_kernel(
    const float* __restrict__ x,
    const float* __restrict__ We1, const float* __restrict__ be1,
    const unsigned int* __restrict__ w2pack, const float* __restrict__ be2,
    const int* __restrict__ gidx, const float* __restrict__ gw,
    float* __restrict__ out)
{
    __shared__ float xs[36 * 40];                             // fp32 x tile + halo2
    __shared__ __align__(16) unsigned short hs[8 * 34 * 36];  // fp16 h, stride 36

    const int tile = blockIdx.x;
    const int b    = blockIdx.y;
    const int ty = tile >> 3, tx = tile & 7;
    const int y0 = ty * 32, x0 = tx * 32;
    const int tid = threadIdx.x;
    const bool interior = (ty != 0) && (ty != 7) && (tx != 0) && (tx != 7);

    const float* xb = x + (size_t)b * (IMG * IMG);
    if (interior) {
        for (int i = tid; i < 36 * 40; i += 256) {
            int r = i / 40, c = i - r * 40;
            xs[i] = xb[(y0 - 2 + r) * IMG + (x0 - 2 + c)];
        }
    } else {
        for (int i = tid; i < 36 * 40; i += 256) {
            int r = i / 40, c = i - r * 40;
            float v = 0.f;
            if (c < 36) {
                int gy = y0 - 2 + r, gx = x0 - 2 + c;
                if (gy >= 0 && gy < IMG && gx >= 0 && gx < IMG) v = xb[gy * IMG + gx];
            }
            xs[i] = v;
        }
    }

    const int ep = __builtin_amdgcn_readfirstlane(gidx[b]);
    const int ec = __builtin_amdgcn_readfirstlane(gidx[64 + b]);
    const float wA = __uint_as_float(__builtin_amdgcn_readfirstlane(__float_as_uint(gw[b])));
    const float wB = __uint_as_float(__builtin_amdgcn_readfirstlane(__float_as_uint(gw[64 + b])));

    const int r_ = tid >> 3;          // 0..31 output row
    const int c0 = (tid & 7) << 2;    // output col group (4 cols)
    const int c1ch   = tid >> 5;      // conv1: channel 0..7
    const int lane32 = tid & 31;

    float oacc0 = 0.f, oacc1 = 0.f, oacc2 = 0.f, oacc3 = 0.f;

    __syncthreads();

    for (int ei = 0; ei < 2; ++ei) {
        const int   e   = ei ? ec : ep;
        const float wgt = ei ? wB : wA;

        float w1r[9];
        const float* w1p = We1 + e * 72 + c1ch * 9;
        #pragma unroll
        for (int k = 0; k < 9; ++k) w1r[k] = w1p[k];
        const float b1r = be1[e * 8 + c1ch];

        if (ei) __syncthreads();   // prev conv2 reads done before hs overwrite

        // ---- conv1: h = relu(conv(x) + b1) in fp16, 4x4 patch per pass ----
        #pragma unroll 1
        for (int t = 0; t < 3; ++t) {
            const int p = lane32 + 32 * t;
            if (p < 81) {
                const int pr = p / 9;
                const int pc = p - pr * 9;
                const int hy0 = pr << 2;
                const int cb  = pc << 2;      // 0,4,...,32

                v2f a01[4], a23[4];
                #pragma unroll
                for (int q = 0; q < 4; ++q) {
                    a01[q] = (v2f){b1r, b1r};
                    a23[q] = (v2f){b1r, b1r};
                }
                #pragma unroll
                for (int r = 0; r < 6; ++r) {
                    const int row = hy0 + r;
                    if (row < 36) {
                        const float* xr = &xs[row * 40 + cb];
                        const v2f P01 = *(const v2f*)(xr);
                        const v2f P23 = *(const v2f*)(xr + 2);
                        const v2f P45 = *(const v2f*)(xr + 4);
                        const v2f P12 = {P01.y, P23.x};
                        const v2f P34 = {P23.y, P45.x};
                        #pragma unroll
                        for (int q = 0; q < 4; ++q) {
                            const int ky = r - q;
                            if (ky >= 0 && ky < 3) {
                                const float wa = w1r[ky * 3 + 0];
                                const float wb = w1r[ky * 3 + 1];
                                const float wcc = w1r[ky * 3 + 2];
                                const v2f wa2 = {wa, wa}, wb2 = {wb, wb}, wc2 = {wcc, wcc};
                                a01[q] = wa2 * P01 + a01[q];
                                a01[q] = wb2 * P12 + a01[q];
                                a01[q] = wc2 * P23 + a01[q];
                                a23[q] = wa2 * P23 + a23[q];
                                a23[q] = wb2 * P34 + a23[q];
                                a23[q] = wc2 * P45 + a23[q];
                            }
                        }
                    }
                }
                if (interior) {
                    #pragma unroll
                    for (int q = 0; q < 4; ++q) {
                        const int hy = hy0 + q;
                        if (hy < 34) {
                            const unsigned int lo = bits4(
                                __builtin_amdgcn_cvt_pkrtz(fmaxf(a01[q].x, 0.f), fmaxf(a01[q].y, 0.f)));
                            const unsigned int hi = bits4(
                                __builtin_amdgcn_cvt_pkrtz(fmaxf(a23[q].x, 0.f), fmaxf(a23[q].y, 0.f)));
                            unsigned short* hp = &hs[c1ch * 1224 + hy * 36 + cb];
                            if (cb < 32) *(uint2*)hp = make_uint2(lo, hi);
                            else         *(unsigned int*)hp = lo;
                        }
                    }
                } else {
                    #pragma unroll
                    for (int q = 0; q < 4; ++q) {
                        const int hy = hy0 + q;
                        if (hy < 34) {
                            const int gy = y0 - 1 + hy;
                            const int gx = x0 - 1 + cb;
                            const bool rowok = (gy >= 0) && (gy < IMG);
                            const float h0 = (rowok && gx >= 0 && gx < IMG) ? fmaxf(a01[q].x, 0.f) : 0.f;
                            const float h1 = (rowok && (gx + 1) < IMG)      ? fmaxf(a01[q].y, 0.f) : 0.f;
                            const float h2 = (rowok && (gx + 2) < IMG)      ? fmaxf(a23[q].x, 0.f) : 0.f;
                            const float h3 = (rowok && (gx + 3) < IMG)      ? fmaxf(a23[q].y, 0.f) : 0.f;
                            const unsigned int lo = bits4(__builtin_amdgcn_cvt_pkrtz(h0, h1));
                            const unsigned int hi = bits4(__builtin_amdgcn_cvt_pkrtz(h2, h3));
                            unsigned short* hp = &hs[c1ch * 1224 + hy * 36 + cb];
                            if (cb < 32) *(uint2*)hp = make_uint2(lo, hi);
                            else         *(unsigned int*)hp = lo;
                        }
                    }
                }
            }
        }
        __syncthreads();

        // ---- conv2 via v_dot2_f32_f16: y = conv(h) + b2 ----
        float a0 = 0.f, a1 = 0.f, a2 = 0.f, a3 = 0.f;
        #pragma unroll
        for (int ch = 0; ch < 8; ++ch) {
            #pragma unroll
            for (int ky = 0; ky < 3; ++ky) {
                const uint4 wp = *(const uint4*)&w2pack[(((e * 8) + ch) * 3 + ky) * 4]; // s_load
                const unsigned short* hp = &hs[ch * 1224 + (r_ + ky) * 36 + c0];
                const uint2 q4 = *(const uint2*)hp;
                const unsigned int q2 = *(const unsigned int*)(hp + 4);
                const half2v P01 = h2bits(q4.x), P23 = h2bits(q4.y), P45 = h2bits(q2);
                const half2v p0 = h2bits(wp.x), p1 = h2bits(wp.y), p2 = h2bits(wp.z), p3 = h2bits(wp.w);
                a0 = __builtin_amdgcn_fdot2(p0, P01, a0, false);
                a0 = __builtin_amdgcn_fdot2(p1, P23, a0, false);
                a1 = __builtin_amdgcn_fdot2(p2, P01, a1, false);
                a1 = __builtin_amdgcn_fdot2(p3, P23, a1, false);
                a2 = __builtin_amdgcn_fdot2(p0, P23, a2, false);
                a2 = __builtin_amdgcn_fdot2(p1, P45, a2, false);
                a3 = __builtin_amdgcn_fdot2(p2, P23, a3, false);
                a3 = __builtin_amdgcn_fdot2(p3, P45, a3, false);
            }
        }
        const float b2v = be2[e];
        oacc0 += wgt * (a0 + b2v);
        oacc1 += wgt * (a1 + b2v);
        oacc2 += wgt * (a2 + b2v);
        oacc3 += wgt * (a3 + b2v);
    }

    const float4 o4 = make_float4(oacc0, oacc1, oacc2, oacc3);
    *(float4*)&out[(size_t)b * (IMG * IMG) + (y0 + r_) * IMG + (x0 + c0)] = o4;
}

extern "C" void kernel_launch(void* const* d_in, const int* in_sizes, int n_in,
                              void* d_out, int out_size, void* d_ws, size_t ws_size,
                              hipStream_t stream) {
    const float* x   = (const float*)d_in[0];
    const float* Wg  = (const float*)d_in[1];
    const float* Wc  = (const float*)d_in[2];
    const float* bc  = (const float*)d_in[3];
    const float* Wp  = (const float*)d_in[4];
    const float* bp  = (const float*)d_in[5];
    const float* We1 = (const float*)d_in[6];
    const float* be1 = (const float*)d_in[7];
    const float* We2 = (const float*)d_in[8];
    const float* be2 = (const float*)d_in[9];
    float* out = (float*)d_out;

    float*        partials = (float*)d_ws;                        // 256 KB
    int*          gidx     = (int*)((char*)d_ws + 262144);        // 512 B
    float*        gw       = (float*)((char*)d_ws + 262656);      // 512 B
    short*        bhi      = (short*)((char*)d_ws + 263168);      // 8 KB
    short*        blo      = (short*)((char*)d_ws + 271360);      // 8 KB
    unsigned int* w2pack   = (unsigned int*)((char*)d_ws + 279552); // 3 KB

    gate_prep_kernel<<<dim3(1), dim3(64), 0, stream>>>(Wg, We2, bhi, blo, w2pack);
    gate_mfma_kernel<<<dim3(16, 64), dim3(256), 0, stream>>>(x, bhi, blo, partials);
    gate_finalize_kernel<<<dim3(1), dim3(256), 0, stream>>>(partials, Wc, bc, Wp, bp, gidx, gw);
    expert_kernel<<<dim3(64, 64), dim3(256), 0, stream>>>(x, We1, be1, w2pack, be2, gidx, gw, out);
}

// Round 11
// 75.550 us; speedup vs baseline: 1.6314x; 1.2673x over previous
//
#include <hip/hip_runtime.h>
#include <hip/hip_bf16.h>
#include <math.h>

#define IMG 256

typedef __attribute__((ext_vector_type(4))) short short4v;
typedef __attribute__((ext_vector_type(8))) short short8v;
typedef __attribute__((ext_vector_type(4))) float f32x4;
typedef __attribute__((ext_vector_type(2))) float v2f;
typedef _Float16 half2v __attribute__((ext_vector_type(2)));

__device__ __forceinline__ short bf16s(float f) {
    __hip_bfloat16 h = __float2bfloat16(f);
    short s; __builtin_memcpy(&s, &h, 2); return s;
}
__device__ __forceinline__ half2v h2bits(unsigned int u) {
    half2v h; __builtin_memcpy(&h, &u, 4); return h;
}
template <typename T>
__device__ __forceinline__ unsigned int bits4(T v) {
    static_assert(sizeof(T) == 4, "bits4 needs 4-byte type");
    unsigned int u; __builtin_memcpy(&u, &v, 4); return u;
}
__device__ __forceinline__ unsigned int h16b(float f) {
    _Float16 h = (_Float16)f;          // RNE
    unsigned short s; __builtin_memcpy(&s, &h, 2); return (unsigned int)s;
}

// ---------------- Kernel 1: gating conv 7x7 s4 + relu + partial sums via MFMA --
// grid (16 tiles = 8 row x 2 col, 64 batch), 256 threads.
// B-frags built inline from Wg (L2-hot); block(0,0) also packs conv2 weights.
__global__ __launch_bounds__(256) void gate_mfma_kernel(
    const float* __restrict__ x, const float* __restrict__ Wg,
    const float* __restrict__ We2,
    float* __restrict__ partials, unsigned int* __restrict__ w2pack)
{
    __shared__ short xs[36 * 136];
    __shared__ float red[4][64];

    const int tile = blockIdx.x;       // 0..15
    const int rt = tile >> 1, ct = tile & 1;
    const int b   = blockIdx.y;
    const int tid = threadIdx.x;

    // ---- x staging, vectorized float4 ----
    const float* xb = x + (size_t)b * (IMG * IMG);
    const int gy0 = rt * 32 - 1;
    {
        const int qx = tid & 31;       // quad -> xs cols 1+4qx .. 4+4qx
        const int rb = tid >> 5;       // 0..7
        #pragma unroll
        for (int t = 0; t < 5; ++t) {
            const int r = rb + 8 * t;
            if (r < 36) {
                const int gy = gy0 + r;
                float4 v = make_float4(0.f, 0.f, 0.f, 0.f);
                if (gy >= 0 && gy < IMG)
                    v = *(const float4*)&xb[gy * IMG + 128 * ct + 4 * qx];
                short* p = &xs[r * 136 + 4 * qx + 1];
                p[0] = bf16s(v.x); p[1] = bf16s(v.y); p[2] = bf16s(v.z); p[3] = bf16s(v.w);
            }
        }
    }
    if (tid < 36) {                    // col 0 (gx = 128ct-1)
        const int r = tid, gy = gy0 + r;
        float v = 0.f;
        if (gy >= 0 && gy < IMG && ct == 1) v = xb[gy * IMG + 127];
        xs[r * 136] = bf16s(v);
    }
    if (tid < 36) {                    // cols 129..132 (gx = 128ct+128..131)
        const int r = tid, gy = gy0 + r;
        float4 v = make_float4(0.f, 0.f, 0.f, 0.f);
        if (gy >= 0 && gy < IMG && ct == 0)
            v = *(const float4*)&xb[gy * IMG + 128];
        short* p = &xs[r * 136 + 129];
        p[0] = bf16s(v.x); p[1] = bf16s(v.y); p[2] = bf16s(v.z); p[3] = bf16s(v.w);
    }

    const int lane = tid & 63;
    const int wv_  = tid >> 6;   // wave 0..3
    const int m    = lane & 15;
    const int kb   = lane >> 4;  // 0..3

    // ---- B fragments built inline (hi+lo bf16 split of Wg) ----
    short8v Bhi[2][4], Blo[2][4];
    #pragma unroll
    for (int s = 0; s < 2; ++s) {
        const int ky = kb + 4 * s;          // 0..7 (7 = zero pad row)
        #pragma unroll
        for (int nc = 0; nc < 4; ++nc) {
            const int gf = nc * 16 + m;
            short8v bh, bl;
            #pragma unroll
            for (int j = 0; j < 8; ++j) {   // kx (7 = zero pad col)
                float wv = 0.f;
                if (j < 7 && ky < 7) wv = Wg[gf * 49 + ky * 7 + j];
                const short hi = bf16s(wv);
                const float hif = __uint_as_float(((unsigned int)(unsigned short)hi) << 16);
                bh[j] = hi;
                bl[j] = bf16s(wv - hif);
            }
            Bhi[s][nc] = bh; Blo[s][nc] = bl;
        }
    }

    __syncthreads();

    float rsum[4] = {0.f, 0.f, 0.f, 0.f};
    const f32x4 zero4 = {0.f, 0.f, 0.f, 0.f};

    #pragma unroll 1
    for (int i = 0; i < 4; ++i) {            // 4 chunks per wave, 16 per block
        const int chunk = wv_ * 4 + i;
        const int r = chunk >> 1, q = chunk & 1;
        short8v A[2];
        #pragma unroll
        for (int s = 0; s < 2; ++s) {
            const int row = 4 * r + kb + 4 * s;
            const short4v* p = (const short4v*)&xs[row * 136 + 64 * q + 4 * m];
            const short4v lo4 = p[0], hi4 = p[1];
            A[s] = __builtin_shufflevector(lo4, hi4, 0, 1, 2, 3, 4, 5, 6, 7);
        }
        #pragma unroll
        for (int nc = 0; nc < 4; ++nc) {
            f32x4 z = __builtin_amdgcn_mfma_f32_16x16x32_bf16(A[0], Bhi[0][nc], zero4, 0, 0, 0);
            z = __builtin_amdgcn_mfma_f32_16x16x32_bf16(A[1], Bhi[1][nc], z, 0, 0, 0);
            z = __builtin_amdgcn_mfma_f32_16x16x32_bf16(A[0], Blo[0][nc], z, 0, 0, 0);
            z = __builtin_amdgcn_mfma_f32_16x16x32_bf16(A[1], Blo[1][nc], z, 0, 0, 0);
            rsum[nc] += fmaxf(z[0], 0.f) + fmaxf(z[1], 0.f) + fmaxf(z[2], 0.f) + fmaxf(z[3], 0.f);
        }
    }

    #pragma unroll
    for (int nc = 0; nc < 4; ++nc) {
        float v = rsum[nc];
        v += __shfl_xor(v, 16);
        v += __shfl_xor(v, 32);
        if (lane < 16) red[wv_][nc * 16 + lane] = v;
    }
    __syncthreads();
    if (tid < 64) {
        const float s = red[0][tid] + red[1][tid] + red[2][tid] + red[3][tid];
        partials[(b * 16 + tile) * 64 + tid] = s;
    }

    // ---- block (0,0): pack conv2 weights for the NEXT kernel (no race) ----
    if (tile == 0 && b == 0) {
        for (int i = tid; i < 192; i += 256) {      // i = (e,ch,ky)
            const int e = i / 24, rem = i - e * 24;
            const int ch = rem / 3, ky = rem - ch * 3;
            const float* wp = We2 + e * 72 + ch * 9 + ky * 3;
            const unsigned int ha = h16b(wp[0]), hb = h16b(wp[1]), hc = h16b(wp[2]);
            w2pack[i * 4 + 0] = ha | (hb << 16);
            w2pack[i * 4 + 1] = hc;
            w2pack[i * 4 + 2] = (ha << 16);
            w2pack[i * 4 + 3] = hb | (hc << 16);
        }
    }
}

// ---------------- Kernel 2: gating decision + two-expert conv-relu-conv -------
// wave 0 computes batch-b gating from partials (hidden under xs staging).
// conv1: 4x4 patches; h in fp16; conv2 via v_dot2_f32_f16.
// grid (64 tiles of 32x32, 64 batch), 256 threads.
__global__ __launch_bounds__(256) void expert_kernel(
    const float* __restrict__ x,
    const float* __restrict__ We1, const float* __restrict__ be1,
    const unsigned int* __restrict__ w2pack, const float* __restrict__ be2,
    const float* __restrict__ partials,
    const float* __restrict__ Wc, const float* __restrict__ bc,
    const float* __restrict__ Wp, const float* __restrict__ bp,
    float* __restrict__ out)
{
    __shared__ float xs[36 * 40];                             // fp32 x tile + halo2
    __shared__ __align__(16) unsigned short hs[8 * 34 * 36];  // fp16 h, stride 36
    __shared__ int   gsh_i[2];
    __shared__ float gsh_w[2];

    const int tile = blockIdx.x;
    const int b    = blockIdx.y;
    const int ty = tile >> 3, tx = tile & 7;
    const int y0 = ty * 32, x0 = tx * 32;
    const int tid = threadIdx.x;
    const bool interior = (ty != 0) && (ty != 7) && (tx != 0) && (tx != 7);

    const float* xb = x + (size_t)b * (IMG * IMG);
    if (interior) {
        for (int i = tid; i < 36 * 40; i += 256) {
            int r = i / 40, c = i - r * 40;
            xs[i] = xb[(y0 - 2 + r) * IMG + (x0 - 2 + c)];
        }
    } else {
        for (int i = tid; i < 36 * 40; i += 256) {
            int r = i / 40, c = i - r * 40;
            float v = 0.f;
            if (c < 36) {
                int gy = y0 - 2 + r, gx = x0 - 2 + c;
                if (gy >= 0 && gy < IMG && gx >= 0 && gx < IMG) v = xb[gy * IMG + gx];
            }
            xs[i] = v;
        }
    }

    // ---- inline gating decision for batch b (wave 0) ----
    if (tid < 64) {
        const int g = tid;
        float f = 0.f;
        const float* pb = partials + b * 1024;
        #pragma unroll
        for (int t = 0; t < 16; ++t) f += pb[t * 64 + g];
        f *= (1.0f / 4096.0f);

        float lg[8];
        #pragma unroll
        for (int j = 0; j < 6; ++j) {
            float p = f * Wc[j * 64 + g];
            p += __shfl_xor(p, 1);  p += __shfl_xor(p, 2);  p += __shfl_xor(p, 4);
            p += __shfl_xor(p, 8);  p += __shfl_xor(p, 16); p += __shfl_xor(p, 32);
            lg[j] = p + bc[j];
        }
        #pragma unroll
        for (int j = 0; j < 2; ++j) {
            float p = f * Wp[j * 64 + g];
            p += __shfl_xor(p, 1);  p += __shfl_xor(p, 2);  p += __shfl_xor(p, 4);
            p += __shfl_xor(p, 8);  p += __shfl_xor(p, 16); p += __shfl_xor(p, 32);
            lg[6 + j] = p + bp[j];
        }
        // all 64 lanes hold identical lg[]
        const float pm = fmaxf(lg[6], lg[7]);
        const float e0 = expf(lg[6] - pm), e1 = expf(lg[7] - pm);
        const int   pi = (lg[7] > lg[6]) ? 1 : 0;
        const float pv = fmaxf(e0, e1) / (e0 + e1);
        float cm = lg[0];
        #pragma unroll
        for (int j = 1; j < 6; ++j) cm = fmaxf(cm, lg[j]);
        float es = 0.f, ce[6];
        #pragma unroll
        for (int j = 0; j < 6; ++j) { ce[j] = expf(lg[j] - cm); es += ce[j]; }
        int ci = 0; float cbest = lg[0];
        #pragma unroll
        for (int j = 1; j < 6; ++j) if (lg[j] > cbest) { cbest = lg[j]; ci = j; }
        const float cv = ce[ci] / es;

        const float wpv = 0.3f * pv;
        const float wcv = 0.7f * cv;
        const float tot = wpv + wcv + 1e-8f;
        if (tid == 0) {
            gsh_i[0] = pi;
            gsh_i[1] = ci + 2;
            gsh_w[0] = wpv / tot;
            gsh_w[1] = wcv / tot;
        }
    }

    __syncthreads();

    const int ep = __builtin_amdgcn_readfirstlane(gsh_i[0]);
    const int ec = __builtin_amdgcn_readfirstlane(gsh_i[1]);
    const float wA = __uint_as_float(__builtin_amdgcn_readfirstlane(__float_as_uint(gsh_w[0])));
    const float wB = __uint_as_float(__builtin_amdgcn_readfirstlane(__float_as_uint(gsh_w[1])));

    const int r_ = tid >> 3;          // 0..31 output row
    const int c0 = (tid & 7) << 2;    // output col group (4 cols)
    const int c1ch   = tid >> 5;      // conv1: channel 0..7
    const int lane32 = tid & 31;

    float oacc0 = 0.f, oacc1 = 0.f, oacc2 = 0.f, oacc3 = 0.f;

    for (int ei = 0; ei < 2; ++ei) {
        const int   e   = ei ? ec : ep;
        const float wgt = ei ? wB : wA;

        float w1r[9];
        const float* w1p = We1 + e * 72 + c1ch * 9;
        #pragma unroll
        for (int k = 0; k < 9; ++k) w1r[k] = w1p[k];
        const float b1r = be1[e * 8 + c1ch];

        if (ei) __syncthreads();   // prev conv2 reads done before hs overwrite

        // ---- conv1: h = relu(conv(x) + b1) in fp16, 4x4 patch per pass ----
        #pragma unroll 1
        for (int t = 0; t < 3; ++t) {
            const int p = lane32 + 32 * t;
            if (p < 81) {
                const int pr = p / 9;
                const int pc = p - pr * 9;
                const int hy0 = pr << 2;
                const int cb  = pc << 2;      // 0,4,...,32

                v2f a01[4], a23[4];
                #pragma unroll
                for (int q = 0; q < 4; ++q) {
                    a01[q] = (v2f){b1r, b1r};
                    a23[q] = (v2f){b1r, b1r};
                }
                #pragma unroll
                for (int r = 0; r < 6; ++r) {
                    const int row = hy0 + r;
                    if (row < 36) {
                        const float* xr = &xs[row * 40 + cb];
                        const v2f P01 = *(const v2f*)(xr);
                        const v2f P23 = *(const v2f*)(xr + 2);
                        const v2f P45 = *(const v2f*)(xr + 4);
                        const v2f P12 = {P01.y, P23.x};
                        const v2f P34 = {P23.y, P45.x};
                        #pragma unroll
                        for (int q = 0; q < 4; ++q) {
                            const int ky = r - q;
                            if (ky >= 0 && ky < 3) {
                                const float wa = w1r[ky * 3 + 0];
                                const float wb = w1r[ky * 3 + 1];
                                const float wcc = w1r[ky * 3 + 2];
                                const v2f wa2 = {wa, wa}, wb2 = {wb, wb}, wc2 = {wcc, wcc};
                                a01[q] = wa2 * P01 + a01[q];
                                a01[q] = wb2 * P12 + a01[q];
                                a01[q] = wc2 * P23 + a01[q];
                                a23[q] = wa2 * P23 + a23[q];
                                a23[q] = wb2 * P34 + a23[q];
                                a23[q] = wc2 * P45 + a23[q];
                            }
                        }
                    }
                }
                if (interior) {
                    #pragma unroll
                    for (int q = 0; q < 4; ++q) {
                        const int hy = hy0 + q;
                        if (hy < 34) {
                            const unsigned int lo = bits4(
                                __builtin_amdgcn_cvt_pkrtz(fmaxf(a01[q].x, 0.f), fmaxf(a01[q].y, 0.f)));
                            const unsigned int hi = bits4(
                                __builtin_amdgcn_cvt_pkrtz(fmaxf(a23[q].x, 0.f), fmaxf(a23[q].y, 0.f)));
                            unsigned short* hp = &hs[c1ch * 1224 + hy * 36 + cb];
                            if (cb < 32) *(uint2*)hp = make_uint2(lo, hi);
                            else         *(unsigned int*)hp = lo;
                        }
                    }
                } else {
                    #pragma unroll
                    for (int q = 0; q < 4; ++q) {
                        const int hy = hy0 + q;
                        if (hy < 34) {
                            const int gy = y0 - 1 + hy;
                            const int gx = x0 - 1 + cb;
                            const bool rowok = (gy >= 0) && (gy < IMG);
                            const float h0 = (rowok && gx >= 0 && gx < IMG) ? fmaxf(a01[q].x, 0.f) : 0.f;
                            const float h1 = (rowok && (gx + 1) < IMG)      ? fmaxf(a01[q].y, 0.f) : 0.f;
                            const float h2 = (rowok && (gx + 2) < IMG)      ? fmaxf(a23[q].x, 0.f) : 0.f;
                            const float h3 = (rowok && (gx + 3) < IMG)      ? fmaxf(a23[q].y, 0.f) : 0.f;
                            const unsigned int lo = bits4(__builtin_amdgcn_cvt_pkrtz(h0, h1));
                            const unsigned int hi = bits4(__builtin_amdgcn_cvt_pkrtz(h2, h3));
                            unsigned short* hp = &hs[c1ch * 1224 + hy * 36 + cb];
                            if (cb < 32) *(uint2*)hp = make_uint2(lo, hi);
                            else         *(unsigned int*)hp = lo;
                        }
                    }
                }
            }
        }
        __syncthreads();

        // ---- conv2 via v_dot2_f32_f16: y = conv(h) + b2 ----
        float a0 = 0.f, a1 = 0.f, a2 = 0.f, a3 = 0.f;
        #pragma unroll
        for (int ch = 0; ch < 8; ++ch) {
            #pragma unroll
            for (int ky = 0; ky < 3; ++ky) {
                const uint4 wp = *(const uint4*)&w2pack[(((e * 8) + ch) * 3 + ky) * 4]; // s_load
                const unsigned short* hp = &hs[ch * 1224 + (r_ + ky) * 36 + c0];
                const uint2 q4 = *(const uint2*)hp;
                const unsigned int q2 = *(const unsigned int*)(hp + 4);
                const half2v P01 = h2bits(q4.x), P23 = h2bits(q4.y), P45 = h2bits(q2);
                const half2v p0 = h2bits(wp.x), p1 = h2bits(wp.y), p2 = h2bits(wp.z), p3 = h2bits(wp.w);
                a0 = __builtin_amdgcn_fdot2(p0, P01, a0, false);
                a0 = __builtin_amdgcn_fdot2(p1, P23, a0, false);
                a1 = __builtin_amdgcn_fdot2(p2, P01, a1, false);
                a1 = __builtin_amdgcn_fdot2(p3, P23, a1, false);
                a2 = __builtin_amdgcn_fdot2(p0, P23, a2, false);
                a2 = __builtin_amdgcn_fdot2(p1, P45, a2, false);
                a3 = __builtin_amdgcn_fdot2(p2, P23, a3, false);
                a3 = __builtin_amdgcn_fdot2(p3, P45, a3, false);
            }
        }
        const float b2v = be2[e];
        oacc0 += wgt * (a0 + b2v);
        oacc1 += wgt * (a1 + b2v);
        oacc2 += wgt * (a2 + b2v);
        oacc3 += wgt * (a3 + b2v);
    }

    const float4 o4 = make_float4(oacc0, oacc1, oacc2, oacc3);
    *(float4*)&out[(size_t)b * (IMG * IMG) + (y0 + r_) * IMG + (x0 + c0)] = o4;
}

extern "C" void kernel_launch(void* const* d_in, const int* in_sizes, int n_in,
                              void* d_out, int out_size, void* d_ws, size_t ws_size,
                              hipStream_t stream) {
    const float* x   = (const float*)d_in[0];
    const float* Wg  = (const float*)d_in[1];
    const float* Wc  = (const float*)d_in[2];
    const float* bc  = (const float*)d_in[3];
    const float* Wp  = (const float*)d_in[4];
    const float* bp  = (const float*)d_in[5];
    const float* We1 = (const float*)d_in[6];
    const float* be1 = (const float*)d_in[7];
    const float* We2 = (const float*)d_in[8];
    const float* be2 = (const float*)d_in[9];
    float* out = (float*)d_out;

    float*        partials = (float*)d_ws;                          // 256 KB
    unsigned int* w2pack   = (unsigned int*)((char*)d_ws + 262144); // 3 KB

    gate_mfma_kernel<<<dim3(16, 64), dim3(256), 0, stream>>>(x, Wg, We2, partials, w2pack);
    expert_kernel<<<dim3(64, 64), dim3(256), 0, stream>>>(x, We1, be1, w2pack, be2,
                                                          partials, Wc, bc, Wp, bp, out);
}